// Round 13
// baseline (274.650 us; speedup 1.0000x reference)
//
#include <hip/hip_runtime.h>
#include <hip/hip_bf16.h>

// ---------------------------------------------------------------------------
// MVoT token processor: out = hidden + MLP_{type}(LN(hidden)), type in {0,1}
// R13 = R12 (makespan fix, validated: 156->108us) with:
//  - tail split-K 4->8: 256 tail blocks (1/CU round), tau_tail ~30->~13us
//  - pad-row-zero kernel (512 rows, <1us) replaces 35.6MB memset (~6us)
//  - weight transposes use 2 slots, second pair done between the GEMMs
// Full path (256 x 256^2 tiles, R4 schedule) untouched.
// ---------------------------------------------------------------------------

#define H_DIM 2048
#define FULLROWS 8192
#define TAILROWS 512
#define KSPLIT 8

typedef __attribute__((ext_vector_type(8))) short s16x8;   // 8 bf16 (4 VGPRs)
typedef __attribute__((ext_vector_type(4))) float f32x4;   // MFMA accumulator
typedef __attribute__((ext_vector_type(4))) int   i32x4;   // asm ds_read dst

typedef __attribute__((address_space(1))) const unsigned int gu32;
typedef __attribute__((address_space(3))) unsigned int lu32;
typedef __attribute__((address_space(3))) short lds_s;

__device__ __forceinline__ void load_lds16(const void* g, void* l) {
  __builtin_amdgcn_global_load_lds((gu32*)g, (lu32*)l, 16, 0, 0);
}

__device__ __forceinline__ s16x8 asbf(i32x4 v) {
  union { i32x4 i; s16x8 s; } u; u.i = v; return u.s;
}

// ---------------------------------------------------------------------------
// Partition (R2-verified): text first, each group padded to 256 rows.
// ctrl: [0]=Mt [1]=Mt_pad [2]=Mi [3]=Mi_pad [4]=total_rows
// ---------------------------------------------------------------------------
__global__ __launch_bounds__(256) void partition_kernel(
    const int* __restrict__ tt, int T, int* __restrict__ ctrl,
    int* __restrict__ pos, int* __restrict__ rowid) {
  __shared__ int psum[256];
  const int tid = threadIdx.x;
  const int npt = T >> 8;
  const int base = tid * npt;
  int cnt = 0;
  for (int i = 0; i < npt; ++i) cnt += (tt[base + i] == 0);
  psum[tid] = cnt;
  __syncthreads();
  for (int off = 1; off < 256; off <<= 1) {
    int v = psum[tid];
    int add = (tid >= off) ? psum[tid - off] : 0;
    __syncthreads();
    psum[tid] = v + add;
    __syncthreads();
  }
  const int Mt = psum[255];
  const int Mt_pad = (Mt + 255) & ~255;
  int tpos = psum[tid] - cnt;
  int ipos = base - tpos;
  for (int i = 0; i < npt; ++i) {
    const int tok = base + i;
    int p;
    if (tt[tok] == 0) p = tpos++;
    else              p = Mt_pad + ipos++;
    pos[tok] = p;
    rowid[p] = tok;
  }
  const int Mi = T - Mt;
  const int Mi_pad = (Mi + 255) & ~255;
  for (int g = Mt + tid; g < Mt_pad; g += 256) rowid[g] = -1;
  for (int g = Mt_pad + Mi + tid; g < Mt_pad + Mi_pad; g += 256) rowid[g] = -1;
  for (int g = Mt_pad + Mi_pad + tid; g < FULLROWS + TAILROWS; g += 256)
    rowid[g] = -1;
  if (tid == 0) {
    ctrl[0] = Mt; ctrl[1] = Mt_pad; ctrl[2] = Mi; ctrl[3] = Mi_pad;
    ctrl[4] = Mt_pad + Mi_pad;
  }
}

// ---------------------------------------------------------------------------
// Zero exactly the xg rows LN doesn't write: [Mt,Mt_pad) u [Mt_pad+Mi, 8704).
// Total is always exactly 512 rows (pad_t + (512 - pad_t)).
// ---------------------------------------------------------------------------
__global__ __launch_bounds__(256) void pad_zero_kernel(
    const int* __restrict__ ctrl, __hip_bfloat16* __restrict__ XG) {
  const int Mt = ctrl[0], Mt_pad = ctrl[1], Mi = ctrl[2];
  const int n1 = Mt_pad - Mt;
  const int start2 = Mt_pad + Mi;
  const int b = blockIdx.x;
  int row;
  if (b < n1) row = Mt + b;
  else {
    const int b2 = b - n1;
    if (start2 + b2 >= FULLROWS + TAILROWS) return;
    row = start2 + b2;
  }
  const int4 z = {0, 0, 0, 0};
  *(int4*)(XG + (size_t)row * H_DIM + threadIdx.x * 8) = z;
}

// ---------------------------------------------------------------------------
// Weight transpose + fp32->bf16: W[k][n] -> WT[n][k] (B^T layout)
// ---------------------------------------------------------------------------
__global__ __launch_bounds__(256) void transpose_to_bf16(
    const float* __restrict__ W, __hip_bfloat16* __restrict__ WT) {
  __shared__ float tile[32][33];
  const int bx = blockIdx.x, by = blockIdx.y;
  const int tid = threadIdx.x;
  const int r = tid >> 3, c4 = (tid & 7) * 4;
  const float4 v = *(const float4*)(W + (size_t)(by * 32 + r) * H_DIM + bx * 32 + c4);
  tile[r][c4 + 0] = v.x; tile[r][c4 + 1] = v.y;
  tile[r][c4 + 2] = v.z; tile[r][c4 + 3] = v.w;
  __syncthreads();
  union { ushort u[4]; ushort4 v4; } pk;
#pragma unroll
  for (int j = 0; j < 4; ++j) {
    __hip_bfloat16 h = __float2bfloat16(tile[c4 + j][r]);
    pk.u[j] = *(const ushort*)&h;
  }
  *(ushort4*)(WT + (size_t)(bx * 32 + r) * H_DIM + by * 32 + c4) = pk.v4;
}

// ---------------------------------------------------------------------------
// LayerNorm (fp32) -> bf16, scatter row to its gathered position.
// ---------------------------------------------------------------------------
__global__ __launch_bounds__(256) void ln_scatter_kernel(
    const float* __restrict__ X, const float* __restrict__ gamma,
    const float* __restrict__ beta, const int* __restrict__ pos,
    __hip_bfloat16* __restrict__ XG) {
  const int t = blockIdx.x, tid = threadIdx.x;
  const float* row = X + (size_t)t * H_DIM;
  float x[8];
  {
    float4 v0 = *(const float4*)(row + tid * 8);
    float4 v1 = *(const float4*)(row + tid * 8 + 4);
    x[0] = v0.x; x[1] = v0.y; x[2] = v0.z; x[3] = v0.w;
    x[4] = v1.x; x[5] = v1.y; x[6] = v1.z; x[7] = v1.w;
  }
  float s = 0.f, q = 0.f;
#pragma unroll
  for (int j = 0; j < 8; ++j) { s += x[j]; q += x[j] * x[j]; }
#pragma unroll
  for (int off = 32; off > 0; off >>= 1) {
    s += __shfl_down(s, off);
    q += __shfl_down(q, off);
  }
  __shared__ float ls[4], lq[4];
  if ((tid & 63) == 0) { ls[tid >> 6] = s; lq[tid >> 6] = q; }
  __syncthreads();
  const float S = ls[0] + ls[1] + ls[2] + ls[3];
  const float Q = lq[0] + lq[1] + lq[2] + lq[3];
  const float mu = S * (1.0f / H_DIM);
  const float var = Q * (1.0f / H_DIM) - mu * mu;
  const float rstd = rsqrtf(var + 1e-12f);
  const int p = pos[t];
  float4 g0 = *(const float4*)(gamma + tid * 8);
  float4 g1 = *(const float4*)(gamma + tid * 8 + 4);
  float4 b0 = *(const float4*)(beta + tid * 8);
  float4 b1 = *(const float4*)(beta + tid * 8 + 4);
  float g[8] = {g0.x, g0.y, g0.z, g0.w, g1.x, g1.y, g1.z, g1.w};
  float b[8] = {b0.x, b0.y, b0.z, b0.w, b1.x, b1.y, b1.z, b1.w};
  union { ushort u[8]; int4 v; } pk;
#pragma unroll
  for (int j = 0; j < 8; ++j) {
    float y = (x[j] - mu) * rstd * g[j] + b[j];
    __hip_bfloat16 h = __float2bfloat16(y);
    pk.u[j] = *(const ushort*)&h;
  }
  *(int4*)(XG + (size_t)p * H_DIM + tid * 8) = pk.v;
}

// --- asm helpers -----------------------------------------------------------
#define DSRD(dst, addr, OFF) \
  asm volatile("ds_read_b128 %0, %1 offset:" OFF : "=v"(dst) : "v"(addr))
#define PBAR asm volatile("s_barrier" ::: "memory")
#define SB0  __builtin_amdgcn_sched_barrier(0)
#define LGKM0 do { \
  asm volatile("s_waitcnt lgkmcnt(0)" ::: "memory"); SB0; } while (0)
#define VM0 asm volatile("s_waitcnt vmcnt(0)" ::: "memory")

__device__ __forceinline__ float gelu_exact(float z) {
  return 0.5f * z * (1.0f + erff(z * 0.70710678118654752f));
}

// ---------------------------------------------------------------------------
// Unified GEMM, grid = 512 x 512 thr:
//  bid < 256: FULL path (R4/R12-verified): 256x256 tile, BK=64, 8 waves of
//    128x64 (acc[8][4]), 4 asm phases/K-tile, vmcnt(4), XOR-swizzled LDS.
//  bid >= 256: TAIL path (R11/R12-verified loop): 128x256 tile, BK=32,
//    K-range = kp*256..+256 (kp=tb&7, 8 inner tiles), rows 8192..8703,
//    fp32 partials to pp[kp][512][2048]. 256 tail blocks = one 1/CU round
//    filling in behind the full round.
// ---------------------------------------------------------------------------
template <int EPI>
__global__ __launch_bounds__(512, 2) void gemmk(
    const __hip_bfloat16* __restrict__ A,
    const __hip_bfloat16* __restrict__ WTt, const __hip_bfloat16* __restrict__ WTi,
    const float* __restrict__ bt, const float* __restrict__ bi,
    const int* __restrict__ ctrl, const int* __restrict__ rowid,
    __hip_bfloat16* __restrict__ Hout,
    const float* __restrict__ resid, float* __restrict__ Out,
    float* __restrict__ pp) {
  constexpr int K = H_DIM;
  const int Mt_pad = ctrl[1];

  __shared__ __align__(16) char smem[131072];
  const unsigned sBase = (unsigned)(uintptr_t)(lds_s*)smem;

  const int tid = threadIdx.x;
  const int w = tid >> 6, l = tid & 63;
  const int bid = blockIdx.x;

  const int srow8 = l >> 3;
  const int sg = (l & 7) ^ srow8;
  const int r16 = l & 15;
  const int r4base = (l >> 4) * 4;
  const int hl = (l & 15) >> 1;
  const int gr = (((l & 1) << 2) | (l >> 4)) ^ hl;

  if (bid < 256) {
    // ===================== FULL PATH (R4/R12 verbatim) ====================
    constexpr int NT = K / 64;          // 32 K-tiles
    const int m0 = (bid >> 3) * 256;
    const int n0 = (bid & 7) * 256;
    const bool is_text = (m0 < Mt_pad);
    const short* Ag = (const short*)A;
    const short* Bg = (const short*)(is_text ? WTt : WTi);
    const float* bias = is_text ? bt : bi;

    const int wm = w >> 2, wn = w & 3;
    const int scol8 = sg * 8;

    auto stageA = [&](int bI, int h, int kk) {
#pragma unroll
      for (int c = 0; c < 2; ++c) {
        const short* src = Ag + (size_t)(m0 + h * 128 + c * 64 + w * 8 + srow8) * K + kk + scol8;
        load_lds16(src, smem + bI * 32768 + h * 16384 + (c * 4096 + w * 512) * 2);
      }
    };
    auto stageB = [&](int bI, int h, int kk) {
#pragma unroll
      for (int c = 0; c < 2; ++c) {
        const short* src = Bg + (size_t)(n0 + h * 128 + c * 64 + w * 8 + srow8) * K + kk + scol8;
        load_lds16(src, smem + 65536 + bI * 32768 + h * 16384 + (c * 4096 + w * 512) * 2);
      }
    };

    int off2[2];
#pragma unroll
    for (int ks = 0; ks < 2; ++ks)
      off2[ks] = r16 * 64 + (((ks * 4 + (l >> 4)) ^ (l & 7)) * 8);

    unsigned ardA[2][2], ardB[2][2];
#pragma unroll
    for (int bI = 0; bI < 2; ++bI)
#pragma unroll
      for (int ks = 0; ks < 2; ++ks) {
        ardA[bI][ks] = sBase + bI * 32768u + (unsigned)(wm * 16384 + off2[ks] * 2);
        ardB[bI][ks] = sBase + 65536u + bI * 32768u +
                       (unsigned)((wn >> 1) * 16384 + ((wn & 1) * 4096 + off2[ks]) * 2);
      }

    i32x4 a[4][2], b[4][2];
    f32x4 acc[8][4];
    const f32x4 zero = {0.f, 0.f, 0.f, 0.f};
#pragma unroll
    for (int i = 0; i < 8; ++i)
#pragma unroll
      for (int j = 0; j < 4; ++j) acc[i][j] = zero;

    auto mfmaQ = [&](int fmBase, int fnBase) {
#pragma unroll
      for (int fm = 0; fm < 4; ++fm)
#pragma unroll
        for (int fn = 0; fn < 2; ++fn)
#pragma unroll
          for (int ks = 0; ks < 2; ++ks)
            acc[fmBase + fm][fnBase + fn] = __builtin_amdgcn_mfma_f32_16x16x32_bf16(
                asbf(a[fm][ks]), asbf(b[fnBase + fn][ks]),
                acc[fmBase + fm][fnBase + fn], 0, 0, 0);
    };

#define TILE(C) do {                                                          \
    DSRD(a[0][0], ardA[C][0], "0");     DSRD(a[0][1], ardA[C][1], "0");       \
    DSRD(a[1][0], ardA[C][0], "2048");  DSRD(a[1][1], ardA[C][1], "2048");    \
    DSRD(a[2][0], ardA[C][0], "4096");  DSRD(a[2][1], ardA[C][1], "4096");    \
    DSRD(a[3][0], ardA[C][0], "6144");  DSRD(a[3][1], ardA[C][1], "6144");    \
    DSRD(b[0][0], ardB[C][0], "0");     DSRD(b[0][1], ardB[C][1], "0");       \
    DSRD(b[1][0], ardB[C][0], "2048");  DSRD(b[1][1], ardB[C][1], "2048");    \
    stageA(C ^ 1, 0, _kA);                                                    \
    PBAR; LGKM0;                                                              \
    __builtin_amdgcn_s_setprio(1); mfmaQ(0, 0); __builtin_amdgcn_s_setprio(0);\
    SB0; PBAR;                                                                \
    DSRD(b[2][0], ardB[C][0], "4096");  DSRD(b[2][1], ardB[C][1], "4096");    \
    DSRD(b[3][0], ardB[C][0], "6144");  DSRD(b[3][1], ardB[C][1], "6144");    \
    stageA(C ^ 1, 1, _kA);                                                    \
    PBAR; LGKM0;                                                              \
    __builtin_amdgcn_s_setprio(1); mfmaQ(0, 2); __builtin_amdgcn_s_setprio(0);\
    SB0; PBAR;                                                                \
    DSRD(a[0][0], ardA[C][0], "8192");  DSRD(a[0][1], ardA[C][1], "8192");    \
    DSRD(a[1][0], ardA[C][0], "10240"); DSRD(a[1][1], ardA[C][1], "10240");   \
    DSRD(a[2][0], ardA[C][0], "12288"); DSRD(a[2][1], ardA[C][1], "12288");   \
    DSRD(a[3][0], ardA[C][0], "14336"); DSRD(a[3][1], ardA[C][1], "14336");   \
    stageB(C, 0, _kB);                                                        \
    PBAR; LGKM0;                                                              \
    __builtin_amdgcn_s_setprio(1); mfmaQ(4, 2); __builtin_amdgcn_s_setprio(0);\
    SB0; PBAR;                                                                \
    stageB(C, 1, _kB);                                                        \
    asm volatile("s_waitcnt vmcnt(4)" ::: "memory");                          \
    PBAR; SB0;                                                                \
    __builtin_amdgcn_s_setprio(1); mfmaQ(4, 0); __builtin_amdgcn_s_setprio(0);\
    SB0; PBAR;                                                                \
  } while (0)

    stageA(0, 0, 0); stageA(0, 1, 0);
    stageB(0, 0, 0); stageB(0, 1, 0);
    stageB(1, 0, 64); stageB(1, 1, 64);
    asm volatile("s_waitcnt vmcnt(4)" ::: "memory");
    PBAR;

    int _kA, _kB;
    for (int t = 0; t < NT; t += 2) {
      _kA = (t + 1 < NT ? t + 1 : NT - 1) * 64;
      _kB = (t + 2 < NT ? t + 2 : NT - 1) * 64;
      TILE(0);
      _kA = (t + 2 < NT ? t + 2 : NT - 1) * 64;
      _kB = (t + 3 < NT ? t + 3 : NT - 1) * 64;
      TILE(1);
    }
#undef TILE
    asm volatile("s_waitcnt vmcnt(0) lgkmcnt(0)" ::: "memory");

    float bb[4];
#pragma unroll
    for (int fn = 0; fn < 4; ++fn) bb[fn] = bias[n0 + wn * 64 + fn * 16 + r16];
    if (EPI == 0) {
#pragma unroll
      for (int fm = 0; fm < 8; ++fm) {
        const int grow = m0 + wm * 128 + fm * 16 + r4base;
#pragma unroll
        for (int fn = 0; fn < 4; ++fn) {
          const int gcol = n0 + wn * 64 + fn * 16 + r16;
          f32x4 v = acc[fm][fn];
#pragma unroll
          for (int i = 0; i < 4; ++i)
            Hout[(size_t)(grow + i) * K + gcol] = __float2bfloat16(gelu_exact(v[i] + bb[fn]));
        }
      }
    } else {
#pragma unroll
      for (int fm = 0; fm < 8; ++fm) {
        const int grow = m0 + wm * 128 + fm * 16 + r4base;
        int rid[4];
#pragma unroll
        for (int i = 0; i < 4; ++i) rid[i] = rowid[grow + i];
#pragma unroll
        for (int fn = 0; fn < 4; ++fn) {
          const int gcol = n0 + wn * 64 + fn * 16 + r16;
          f32x4 v = acc[fm][fn];
#pragma unroll
          for (int i = 0; i < 4; ++i) {
            if (rid[i] >= 0) {
              const size_t o = (size_t)rid[i] * K + gcol;
              Out[o] = resid[o] + v[i] + bb[fn];
            }
          }
        }
      }
    }
  } else {
    // ============== TAIL PATH (R11/R12 loop, KSPLIT=8) ====================
    const int tb = bid - 256;           // 0..255
    const int kp = tb & 7;
    const int n0 = ((tb >> 3) & 7) * 256;
    const int m0 = FULLROWS + (tb >> 6) * 128;
    const int kk0 = kp * 256;           // K range [kk0, kk0+256), 8 K-tiles
    const bool is_text = (m0 < Mt_pad);
    const short* Ag = (const short*)A;
    const short* Bg = (const short*)(is_text ? WTt : WTi);

    const int wm = w >> 2, wn = w & 3;
    const int sRowAdj = sg >> 2;
    const int sKAdj = (sg & 3) * 8;

    auto stageA = [&](int bI, int kk) {
      const int mr = w * 8 + srow8;
      const short* src = Ag + (size_t)(m0 + mr * 2 + sRowAdj) * K + kk + sKAdj;
      load_lds16(src, smem + bI * 8192 + w * 1024);
    };
    auto stageB = [&](int bI, int c2, int kk) {
      const int mr = c2 * 64 + w * 8 + srow8;
      const short* src = Bg + (size_t)(n0 + mr * 2 + sRowAdj) * K + kk + sKAdj;
      load_lds16(src, smem + 16384 + bI * 16384 + c2 * 8192 + w * 1024);
    };

    unsigned ardA[2], ardB[2];
#pragma unroll
    for (int bI = 0; bI < 2; ++bI) {
      ardA[bI] = sBase + bI * 8192u + (unsigned)(wm * 4096 + hl * 128 + gr * 16);
      ardB[bI] = sBase + 16384u + bI * 16384u + (unsigned)(wn * 4096 + hl * 128 + gr * 16);
    }

    i32x4 a[4], b[4];
    f32x4 acc[4][4];
    const f32x4 zero = {0.f, 0.f, 0.f, 0.f};
#pragma unroll
    for (int i = 0; i < 4; ++i)
#pragma unroll
      for (int j = 0; j < 4; ++j) acc[i][j] = zero;

#define RD_TILE(C) do {                                                   \
    DSRD(a[0], ardA[C], "0");    DSRD(a[1], ardA[C], "1024");             \
    DSRD(a[2], ardA[C], "2048"); DSRD(a[3], ardA[C], "3072");             \
    DSRD(b[0], ardB[C], "0");    DSRD(b[1], ardB[C], "1024");             \
    DSRD(b[2], ardB[C], "2048"); DSRD(b[3], ardB[C], "3072");             \
  } while (0)

    stageA(0, kk0);
    stageB(0, 0, kk0); stageB(0, 1, kk0);
    VM0;
    PBAR;

    for (int i = 0; i < 8; ++i) {
      const int c = i & 1;
      const int kn = kk0 + (i + 1 < 8 ? i + 1 : 7) * 32;
      stageA(c ^ 1, kn);
      stageB(c ^ 1, 0, kn); stageB(c ^ 1, 1, kn);
      RD_TILE(c);
      LGKM0;
      __builtin_amdgcn_s_setprio(1);
#pragma unroll
      for (int f = 0; f < 4; ++f)
#pragma unroll
        for (int fn = 0; fn < 4; ++fn)
          acc[f][fn] = __builtin_amdgcn_mfma_f32_16x16x32_bf16(
              asbf(a[f]), asbf(b[fn]), acc[f][fn], 0, 0, 0);
      __builtin_amdgcn_s_setprio(0);
      SB0;
      VM0;
      PBAR;
    }
#undef RD_TILE
    asm volatile("s_waitcnt vmcnt(0) lgkmcnt(0)" ::: "memory");

    // raw fp32 partial write: pp[kp][512][2048]
    float* ppk = pp + (size_t)kp * TAILROWS * H_DIM;
    const int mrel = m0 - FULLROWS;
#pragma unroll
    for (int fm = 0; fm < 4; ++fm) {
      const int prow = mrel + wm * 64 + fm * 16 + r4base;
#pragma unroll
      for (int fn = 0; fn < 4; ++fn) {
        const int gcol = n0 + wn * 64 + fn * 16 + r16;
        f32x4 v = acc[fm][fn];
#pragma unroll
        for (int i = 0; i < 4; ++i)
          ppk[(size_t)(prow + i) * H_DIM + gcol] = v[i];
      }
    }
  }
}

// ---------------------------------------------------------------------------
// Combine: sum KSPLIT K-partials for tail rows 8192..8703, apply epilogue.
// ---------------------------------------------------------------------------
template <int EPI>
__global__ __launch_bounds__(256) void combine_kernel(
    const float* __restrict__ pp, const float* __restrict__ bt,
    const float* __restrict__ bi, const int* __restrict__ ctrl,
    const int* __restrict__ rowid, __hip_bfloat16* __restrict__ Hout,
    const float* __restrict__ resid, float* __restrict__ Out) {
  const int u = blockIdx.x * 256 + threadIdx.x;      // 0..262143
  const int r = u >> 9;                              // 0..511
  const int c = (u & 511) * 4;
  const size_t off = (size_t)r * H_DIM + c;
  float4 s = *(const float4*)(pp + off);
#pragma unroll
  for (int k = 1; k < KSPLIT; ++k) {
    const float4 sk = *(const float4*)(pp + (size_t)k * TAILROWS * H_DIM + off);
    s.x += sk.x; s.y += sk.y; s.z += sk.z; s.w += sk.w;
  }
  const int grow = FULLROWS + r;
  const float* bias = (grow < ctrl[1]) ? bt : bi;
  const float4 bb = *(const float4*)(bias + c);
  if (EPI == 0) {
    union { ushort u4[4]; ushort4 v4; } pk;
    float z[4] = {s.x + bb.x, s.y + bb.y, s.z + bb.z, s.w + bb.w};
#pragma unroll
    for (int j = 0; j < 4; ++j) {
      __hip_bfloat16 h = __float2bfloat16(0.5f * z[j] * (1.0f + erff(z[j] * 0.70710678118654752f)));
      pk.u4[j] = *(const ushort*)&h;
    }
    *(ushort4*)(Hout + (size_t)grow * H_DIM + c) = pk.v4;
  } else {
    const int rid = rowid[grow];
    if (rid >= 0) {
      const size_t o = (size_t)rid * H_DIM + c;
      const float4 rv = *(const float4*)(resid + o);
      float4 ov;
      ov.x = rv.x + s.x + bb.x; ov.y = rv.y + s.y + bb.y;
      ov.z = rv.z + s.z + bb.z; ov.w = rv.w + s.w + bb.w;
      *(float4*)(Out + o) = ov;
    }
  }
}

// ---------------------------------------------------------------------------
extern "C" void kernel_launch(void* const* d_in, const int* in_sizes, int n_in,
                              void* d_out, int out_size, void* d_ws, size_t ws_size,
                              hipStream_t stream) {
  const float* hidden = (const float*)d_in[0];
  const int*   tt     = (const int*)d_in[1];
  const float* gamma  = (const float*)d_in[2];
  const float* beta   = (const float*)d_in[3];
  const float* tw1    = (const float*)d_in[4];
  const float* tb1    = (const float*)d_in[5];
  const float* tw2    = (const float*)d_in[6];
  const float* tb2    = (const float*)d_in[7];
  const float* iw1    = (const float*)d_in[8];
  const float* ib1    = (const float*)d_in[9];
  const float* iw2    = (const float*)d_in[10];
  const float* ib2    = (const float*)d_in[11];
  float* out = (float*)d_out;

  const int T = in_sizes[1];          // 8192 tokens
  const int K = H_DIM;
  const int maxrows = FULLROWS + TAILROWS;   // 8704

  char* ws = (char*)d_ws;
  int* ctrl  = (int*)(ws);
  int* pos   = (int*)(ws + 4096);
  int* rowid = (int*)(ws + 65536);
  const size_t WOFF = 131072;
  const size_t WSZ = (size_t)K * K * sizeof(__hip_bfloat16);
  // 2 weight slots, reused between GEMM stages
  __hip_bfloat16* wTs0 = (__hip_bfloat16*)(ws + WOFF);
  __hip_bfloat16* wTs1 = (__hip_bfloat16*)(ws + WOFF + WSZ);
  __hip_bfloat16* xg   = (__hip_bfloat16*)(ws + WOFF + 2 * WSZ);
  __hip_bfloat16* hb   = xg + (size_t)maxrows * K;
  float* pp = (float*)(hb + (size_t)maxrows * K);   // 8*512*2048 fp32 = 33.5 MB

  partition_kernel<<<1, 256, 0, stream>>>(tt, T, ctrl, pos, rowid);
  pad_zero_kernel<<<512, 256, 0, stream>>>(ctrl, xg);

  dim3 tg(K / 32, K / 32);
  transpose_to_bf16<<<tg, 256, 0, stream>>>(tw1, wTs0);
  transpose_to_bf16<<<tg, 256, 0, stream>>>(iw1, wTs1);

  ln_scatter_kernel<<<T, 256, 0, stream>>>(hidden, gamma, beta, pos, xg);

  gemmk<0><<<512, 512, 0, stream>>>(xg, wTs0, wTs1, tb1, ib1, ctrl, rowid,
                                    hb, nullptr, nullptr, pp);
  combine_kernel<0><<<1024, 256, 0, stream>>>(pp, tb1, ib1, ctrl, rowid,
                                              hb, nullptr, nullptr);

  transpose_to_bf16<<<tg, 256, 0, stream>>>(tw2, wTs0);
  transpose_to_bf16<<<tg, 256, 0, stream>>>(iw2, wTs1);

  gemmk<1><<<512, 512, 0, stream>>>(hb, wTs0, wTs1, tb2, ib2, ctrl, rowid,
                                    nullptr, hidden, out, pp);
  combine_kernel<1><<<1024, 256, 0, stream>>>(pp, tb2, ib2, ctrl, rowid,
                                              nullptr, hidden, out);
}

// Round 14
// 272.252 us; speedup vs baseline: 1.0088x; 1.0088x over previous
//
#include <hip/hip_runtime.h>
#include <hip/hip_bf16.h>

// ---------------------------------------------------------------------------
// MVoT token processor: out = hidden + MLP_{type}(LN(hidden)), type in {0,1}
// R14: tail blocks now REUSE the R4 4-phase pipeline (2.4us/BK64-tile) as
// K-split-8 256^2 tiles: 128 tail blocks x 4 K-tiles (~11us) vs R12's serial
// 30us / R13's ~45us. Grid 384 = 256 full (R4 verbatim, 78us round) + 128
// tail (partial->pp). Combine sums 8 partials. pad-zero + 2-slot weights.
// ---------------------------------------------------------------------------

#define H_DIM 2048
#define FULLROWS 8192
#define TAILROWS 512
#define KSPLIT 8

typedef __attribute__((ext_vector_type(8))) short s16x8;   // 8 bf16 (4 VGPRs)
typedef __attribute__((ext_vector_type(4))) float f32x4;   // MFMA accumulator
typedef __attribute__((ext_vector_type(4))) int   i32x4;   // asm ds_read dst

typedef __attribute__((address_space(1))) const unsigned int gu32;
typedef __attribute__((address_space(3))) unsigned int lu32;
typedef __attribute__((address_space(3))) short lds_s;

__device__ __forceinline__ void load_lds16(const void* g, void* l) {
  __builtin_amdgcn_global_load_lds((gu32*)g, (lu32*)l, 16, 0, 0);
}

__device__ __forceinline__ s16x8 asbf(i32x4 v) {
  union { i32x4 i; s16x8 s; } u; u.i = v; return u.s;
}

// ---------------------------------------------------------------------------
// Partition (R2-verified): text first, each group padded to 256 rows.
// ctrl: [0]=Mt [1]=Mt_pad [2]=Mi [3]=Mi_pad [4]=total_rows
// ---------------------------------------------------------------------------
__global__ __launch_bounds__(256) void partition_kernel(
    const int* __restrict__ tt, int T, int* __restrict__ ctrl,
    int* __restrict__ pos, int* __restrict__ rowid) {
  __shared__ int psum[256];
  const int tid = threadIdx.x;
  const int npt = T >> 8;
  const int base = tid * npt;
  int cnt = 0;
  for (int i = 0; i < npt; ++i) cnt += (tt[base + i] == 0);
  psum[tid] = cnt;
  __syncthreads();
  for (int off = 1; off < 256; off <<= 1) {
    int v = psum[tid];
    int add = (tid >= off) ? psum[tid - off] : 0;
    __syncthreads();
    psum[tid] = v + add;
    __syncthreads();
  }
  const int Mt = psum[255];
  const int Mt_pad = (Mt + 255) & ~255;
  int tpos = psum[tid] - cnt;
  int ipos = base - tpos;
  for (int i = 0; i < npt; ++i) {
    const int tok = base + i;
    int p;
    if (tt[tok] == 0) p = tpos++;
    else              p = Mt_pad + ipos++;
    pos[tok] = p;
    rowid[p] = tok;
  }
  const int Mi = T - Mt;
  const int Mi_pad = (Mi + 255) & ~255;
  for (int g = Mt + tid; g < Mt_pad; g += 256) rowid[g] = -1;
  for (int g = Mt_pad + Mi + tid; g < Mt_pad + Mi_pad; g += 256) rowid[g] = -1;
  for (int g = Mt_pad + Mi_pad + tid; g < FULLROWS + TAILROWS; g += 256)
    rowid[g] = -1;
  if (tid == 0) {
    ctrl[0] = Mt; ctrl[1] = Mt_pad; ctrl[2] = Mi; ctrl[3] = Mi_pad;
    ctrl[4] = Mt_pad + Mi_pad;
  }
}

// ---------------------------------------------------------------------------
// Zero exactly the xg rows LN doesn't write: [Mt,Mt_pad) u [Mt_pad+Mi, 8704).
// Always exactly 512 rows total.
// ---------------------------------------------------------------------------
__global__ __launch_bounds__(256) void pad_zero_kernel(
    const int* __restrict__ ctrl, __hip_bfloat16* __restrict__ XG) {
  const int Mt = ctrl[0], Mt_pad = ctrl[1], Mi = ctrl[2];
  const int n1 = Mt_pad - Mt;
  const int start2 = Mt_pad + Mi;
  const int b = blockIdx.x;
  int row;
  if (b < n1) row = Mt + b;
  else {
    const int b2 = b - n1;
    if (start2 + b2 >= FULLROWS + TAILROWS) return;
    row = start2 + b2;
  }
  const int4 z = {0, 0, 0, 0};
  *(int4*)(XG + (size_t)row * H_DIM + threadIdx.x * 8) = z;
}

// ---------------------------------------------------------------------------
// Weight transpose + fp32->bf16: W[k][n] -> WT[n][k] (B^T layout)
// ---------------------------------------------------------------------------
__global__ __launch_bounds__(256) void transpose_to_bf16(
    const float* __restrict__ W, __hip_bfloat16* __restrict__ WT) {
  __shared__ float tile[32][33];
  const int bx = blockIdx.x, by = blockIdx.y;
  const int tid = threadIdx.x;
  const int r = tid >> 3, c4 = (tid & 7) * 4;
  const float4 v = *(const float4*)(W + (size_t)(by * 32 + r) * H_DIM + bx * 32 + c4);
  tile[r][c4 + 0] = v.x; tile[r][c4 + 1] = v.y;
  tile[r][c4 + 2] = v.z; tile[r][c4 + 3] = v.w;
  __syncthreads();
  union { ushort u[4]; ushort4 v4; } pk;
#pragma unroll
  for (int j = 0; j < 4; ++j) {
    __hip_bfloat16 h = __float2bfloat16(tile[c4 + j][r]);
    pk.u[j] = *(const ushort*)&h;
  }
  *(ushort4*)(WT + (size_t)(bx * 32 + r) * H_DIM + by * 32 + c4) = pk.v4;
}

// ---------------------------------------------------------------------------
// LayerNorm (fp32) -> bf16, scatter row to its gathered position.
// ---------------------------------------------------------------------------
__global__ __launch_bounds__(256) void ln_scatter_kernel(
    const float* __restrict__ X, const float* __restrict__ gamma,
    const float* __restrict__ beta, const int* __restrict__ pos,
    __hip_bfloat16* __restrict__ XG) {
  const int t = blockIdx.x, tid = threadIdx.x;
  const float* row = X + (size_t)t * H_DIM;
  float x[8];
  {
    float4 v0 = *(const float4*)(row + tid * 8);
    float4 v1 = *(const float4*)(row + tid * 8 + 4);
    x[0] = v0.x; x[1] = v0.y; x[2] = v0.z; x[3] = v0.w;
    x[4] = v1.x; x[5] = v1.y; x[6] = v1.z; x[7] = v1.w;
  }
  float s = 0.f, q = 0.f;
#pragma unroll
  for (int j = 0; j < 8; ++j) { s += x[j]; q += x[j] * x[j]; }
#pragma unroll
  for (int off = 32; off > 0; off >>= 1) {
    s += __shfl_down(s, off);
    q += __shfl_down(q, off);
  }
  __shared__ float ls[4], lq[4];
  if ((tid & 63) == 0) { ls[tid >> 6] = s; lq[tid >> 6] = q; }
  __syncthreads();
  const float S = ls[0] + ls[1] + ls[2] + ls[3];
  const float Q = lq[0] + lq[1] + lq[2] + lq[3];
  const float mu = S * (1.0f / H_DIM);
  const float var = Q * (1.0f / H_DIM) - mu * mu;
  const float rstd = rsqrtf(var + 1e-12f);
  const int p = pos[t];
  float4 g0 = *(const float4*)(gamma + tid * 8);
  float4 g1 = *(const float4*)(gamma + tid * 8 + 4);
  float4 b0 = *(const float4*)(beta + tid * 8);
  float4 b1 = *(const float4*)(beta + tid * 8 + 4);
  float g[8] = {g0.x, g0.y, g0.z, g0.w, g1.x, g1.y, g1.z, g1.w};
  float b[8] = {b0.x, b0.y, b0.z, b0.w, b1.x, b1.y, b1.z, b1.w};
  union { ushort u[8]; int4 v; } pk;
#pragma unroll
  for (int j = 0; j < 8; ++j) {
    float y = (x[j] - mu) * rstd * g[j] + b[j];
    __hip_bfloat16 h = __float2bfloat16(y);
    pk.u[j] = *(const ushort*)&h;
  }
  *(int4*)(XG + (size_t)p * H_DIM + tid * 8) = pk.v;
}

// --- asm helpers -----------------------------------------------------------
#define DSRD(dst, addr, OFF) \
  asm volatile("ds_read_b128 %0, %1 offset:" OFF : "=v"(dst) : "v"(addr))
#define PBAR asm volatile("s_barrier" ::: "memory")
#define SB0  __builtin_amdgcn_sched_barrier(0)
#define LGKM0 do { \
  asm volatile("s_waitcnt lgkmcnt(0)" ::: "memory"); SB0; } while (0)

__device__ __forceinline__ float gelu_exact(float z) {
  return 0.5f * z * (1.0f + erff(z * 0.70710678118654752f));
}

// ---------------------------------------------------------------------------
// Unified GEMM, grid = 384 x 512 thr; single R4 4-phase pipeline for all
// blocks, parameterized (m0, n0, kbase, ntiles, partial):
//  bid < 256: FULL. m0=(bid>>3)*256 (rows 0..8191), n0=(bid&7)*256,
//    kbase=0, ntiles=32, direct epilogue.
//  bid >= 256: TAIL K-split. tb=bid-256 (0..127): kp=tb&7, pos=tb>>3 (0..15),
//    n0=(pos&7)*256, m0=8192+(pos>>3)*256, kbase=kp*256, ntiles=4,
//    fp32 partial write to pp[kp][512][2048]. tau ~= 78*(4/32)+prologue ~11us;
//    128 tail blocks fill in behind the 256-block full round.
// ---------------------------------------------------------------------------
template <int EPI>
__global__ __launch_bounds__(512, 2) void gemmk(
    const __hip_bfloat16* __restrict__ A,
    const __hip_bfloat16* __restrict__ WTt, const __hip_bfloat16* __restrict__ WTi,
    const float* __restrict__ bt, const float* __restrict__ bi,
    const int* __restrict__ ctrl, const int* __restrict__ rowid,
    __hip_bfloat16* __restrict__ Hout,
    const float* __restrict__ resid, float* __restrict__ Out,
    float* __restrict__ pp) {
  constexpr int K = H_DIM;
  const int Mt_pad = ctrl[1];

  __shared__ __align__(16) char smem[131072];
  const unsigned sBase = (unsigned)(uintptr_t)(lds_s*)smem;

  const int tid = threadIdx.x;
  const int w = tid >> 6, l = tid & 63;
  const int bid = blockIdx.x;

  // block geometry
  int m0, n0, kbase, ntiles, kp;
  bool partial;
  if (bid < 256) {
    m0 = (bid >> 3) * 256; n0 = (bid & 7) * 256;
    kbase = 0; ntiles = 32; kp = 0; partial = false;
  } else {
    const int tb = bid - 256;          // 0..127
    kp = tb & 7;
    const int posn = tb >> 3;          // 0..15
    n0 = (posn & 7) * 256;
    m0 = FULLROWS + (posn >> 3) * 256; // 8192 or 8448
    kbase = kp * 256; ntiles = 4; partial = true;
  }
  const bool is_text = (m0 < Mt_pad);
  const short* Ag = (const short*)A;
  const short* Bg = (const short*)(is_text ? WTt : WTi);
  const float* bias = is_text ? bt : bi;

  const int wm = w >> 2, wn = w & 3;
  const int srow8 = l >> 3;
  const int sg = (l & 7) ^ srow8;
  const int scol8 = sg * 8;
  const int r16 = l & 15;
  const int r4base = (l >> 4) * 4;

  auto stageA = [&](int bI, int h, int kk) {
#pragma unroll
    for (int c = 0; c < 2; ++c) {
      const short* src = Ag + (size_t)(m0 + h * 128 + c * 64 + w * 8 + srow8) * K + kk + scol8;
      load_lds16(src, smem + bI * 32768 + h * 16384 + (c * 4096 + w * 512) * 2);
    }
  };
  auto stageB = [&](int bI, int h, int kk) {
#pragma unroll
    for (int c = 0; c < 2; ++c) {
      const short* src = Bg + (size_t)(n0 + h * 128 + c * 64 + w * 8 + srow8) * K + kk + scol8;
      load_lds16(src, smem + 65536 + bI * 32768 + h * 16384 + (c * 4096 + w * 512) * 2);
    }
  };

  int off2[2];
#pragma unroll
  for (int ks = 0; ks < 2; ++ks)
    off2[ks] = r16 * 64 + (((ks * 4 + (l >> 4)) ^ (l & 7)) * 8);

  unsigned ardA[2][2], ardB[2][2];
#pragma unroll
  for (int bI = 0; bI < 2; ++bI)
#pragma unroll
    for (int ks = 0; ks < 2; ++ks) {
      ardA[bI][ks] = sBase + bI * 32768u + (unsigned)(wm * 16384 + off2[ks] * 2);
      ardB[bI][ks] = sBase + 65536u + bI * 32768u +
                     (unsigned)((wn >> 1) * 16384 + ((wn & 1) * 4096 + off2[ks]) * 2);
    }

  i32x4 a[4][2], b[4][2];
  f32x4 acc[8][4];
  const f32x4 zero = {0.f, 0.f, 0.f, 0.f};
#pragma unroll
  for (int i = 0; i < 8; ++i)
#pragma unroll
    for (int j = 0; j < 4; ++j) acc[i][j] = zero;

  auto mfmaQ = [&](int fmBase, int fnBase) {
#pragma unroll
    for (int fm = 0; fm < 4; ++fm)
#pragma unroll
      for (int fn = 0; fn < 2; ++fn)
#pragma unroll
        for (int ks = 0; ks < 2; ++ks)
          acc[fmBase + fm][fnBase + fn] = __builtin_amdgcn_mfma_f32_16x16x32_bf16(
              asbf(a[fm][ks]), asbf(b[fnBase + fn][ks]),
              acc[fmBase + fm][fnBase + fn], 0, 0, 0);
  };

#define TILE(C) do {                                                          \
    DSRD(a[0][0], ardA[C][0], "0");     DSRD(a[0][1], ardA[C][1], "0");       \
    DSRD(a[1][0], ardA[C][0], "2048");  DSRD(a[1][1], ardA[C][1], "2048");    \
    DSRD(a[2][0], ardA[C][0], "4096");  DSRD(a[2][1], ardA[C][1], "4096");    \
    DSRD(a[3][0], ardA[C][0], "6144");  DSRD(a[3][1], ardA[C][1], "6144");    \
    DSRD(b[0][0], ardB[C][0], "0");     DSRD(b[0][1], ardB[C][1], "0");       \
    DSRD(b[1][0], ardB[C][0], "2048");  DSRD(b[1][1], ardB[C][1], "2048");    \
    stageA(C ^ 1, 0, _kA);                                                    \
    PBAR; LGKM0;                                                              \
    __builtin_amdgcn_s_setprio(1); mfmaQ(0, 0); __builtin_amdgcn_s_setprio(0);\
    SB0; PBAR;                                                                \
    DSRD(b[2][0], ardB[C][0], "4096");  DSRD(b[2][1], ardB[C][1], "4096");    \
    DSRD(b[3][0], ardB[C][0], "6144");  DSRD(b[3][1], ardB[C][1], "6144");    \
    stageA(C ^ 1, 1, _kA);                                                    \
    PBAR; LGKM0;                                                              \
    __builtin_amdgcn_s_setprio(1); mfmaQ(0, 2); __builtin_amdgcn_s_setprio(0);\
    SB0; PBAR;                                                                \
    DSRD(a[0][0], ardA[C][0], "8192");  DSRD(a[0][1], ardA[C][1], "8192");    \
    DSRD(a[1][0], ardA[C][0], "10240"); DSRD(a[1][1], ardA[C][1], "10240");   \
    DSRD(a[2][0], ardA[C][0], "12288"); DSRD(a[2][1], ardA[C][1], "12288");   \
    DSRD(a[3][0], ardA[C][0], "14336"); DSRD(a[3][1], ardA[C][1], "14336");   \
    stageB(C, 0, _kB);                                                        \
    PBAR; LGKM0;                                                              \
    __builtin_amdgcn_s_setprio(1); mfmaQ(4, 2); __builtin_amdgcn_s_setprio(0);\
    SB0; PBAR;                                                                \
    stageB(C, 1, _kB);                                                        \
    asm volatile("s_waitcnt vmcnt(4)" ::: "memory");                          \
    PBAR; SB0;                                                                \
    __builtin_amdgcn_s_setprio(1); mfmaQ(4, 0); __builtin_amdgcn_s_setprio(0);\
    SB0; PBAR;                                                                \
  } while (0)

  // prologue (tiles kbase+0, kbase+64 exist for both ntiles=32 and 4)
  stageA(0, 0, kbase); stageA(0, 1, kbase);
  stageB(0, 0, kbase); stageB(0, 1, kbase);
  stageB(1, 0, kbase + 64); stageB(1, 1, kbase + 64);
  asm volatile("s_waitcnt vmcnt(4)" ::: "memory");
  PBAR;

  int _kA, _kB;
  for (int t = 0; t < ntiles; t += 2) {
    _kA = kbase + (t + 1 < ntiles ? t + 1 : ntiles - 1) * 64;
    _kB = kbase + (t + 2 < ntiles ? t + 2 : ntiles - 1) * 64;
    TILE(0);
    _kA = kbase + (t + 2 < ntiles ? t + 2 : ntiles - 1) * 64;
    _kB = kbase + (t + 3 < ntiles ? t + 3 : ntiles - 1) * 64;
    TILE(1);
  }
#undef TILE
  asm volatile("s_waitcnt vmcnt(0) lgkmcnt(0)" ::: "memory");

  if (!partial) {
    float bb[4];
#pragma unroll
    for (int fn = 0; fn < 4; ++fn) bb[fn] = bias[n0 + wn * 64 + fn * 16 + r16];
    if (EPI == 0) {
#pragma unroll
      for (int fm = 0; fm < 8; ++fm) {
        const int grow = m0 + wm * 128 + fm * 16 + r4base;
#pragma unroll
        for (int fn = 0; fn < 4; ++fn) {
          const int gcol = n0 + wn * 64 + fn * 16 + r16;
          f32x4 v = acc[fm][fn];
#pragma unroll
          for (int i = 0; i < 4; ++i)
            Hout[(size_t)(grow + i) * K + gcol] = __float2bfloat16(gelu_exact(v[i] + bb[fn]));
        }
      }
    } else {
#pragma unroll
      for (int fm = 0; fm < 8; ++fm) {
        const int grow = m0 + wm * 128 + fm * 16 + r4base;
        int rid[4];
#pragma unroll
        for (int i = 0; i < 4; ++i) rid[i] = rowid[grow + i];
#pragma unroll
        for (int fn = 0; fn < 4; ++fn) {
          const int gcol = n0 + wn * 64 + fn * 16 + r16;
          f32x4 v = acc[fm][fn];
#pragma unroll
          for (int i = 0; i < 4; ++i) {
            if (rid[i] >= 0) {
              const size_t o = (size_t)rid[i] * K + gcol;
              Out[o] = resid[o] + v[i] + bb[fn];
            }
          }
        }
      }
    }
  } else {
    // fp32 partial write: pp[kp][512][2048]
    float* ppk = pp + (size_t)kp * TAILROWS * H_DIM;
    const int mrel = m0 - FULLROWS;     // 0 or 256
#pragma unroll
    for (int fm = 0; fm < 8; ++fm) {
      const int prow = mrel + wm * 128 + fm * 16 + r4base;
#pragma unroll
      for (int fn = 0; fn < 4; ++fn) {
        const int gcol = n0 + wn * 64 + fn * 16 + r16;
        f32x4 v = acc[fm][fn];
#pragma unroll
        for (int i = 0; i < 4; ++i)
          ppk[(size_t)(prow + i) * H_DIM + gcol] = v[i];
      }
    }
  }
}

// ---------------------------------------------------------------------------
// Combine: sum KSPLIT K-partials for tail rows 8192..8703, apply epilogue.
// ---------------------------------------------------------------------------
template <int EPI>
__global__ __launch_bounds__(256) void combine_kernel(
    const float* __restrict__ pp, const float* __restrict__ bt,
    const float* __restrict__ bi, const int* __restrict__ ctrl,
    const int* __restrict__ rowid, __hip_bfloat16* __restrict__ Hout,
    const float* __restrict__ resid, float* __restrict__ Out) {
  const int u = blockIdx.x * 256 + threadIdx.x;      // 0..262143
  const int r = u >> 9;                              // 0..511
  const int c = (u & 511) * 4;
  const size_t off = (size_t)r * H_DIM + c;
  float4 s = *(const float4*)(pp + off);
#pragma unroll
  for (int k = 1; k < KSPLIT; ++k) {
    const float4 sk = *(const float4*)(pp + (size_t)k * TAILROWS * H_DIM + off);
    s.x += sk.x; s.y += sk.y; s.z += sk.z; s.w += sk.w;
  }
  const int grow = FULLROWS + r;
  const float* bias = (grow < ctrl[1]) ? bt : bi;
  const float4 bb = *(const float4*)(bias + c);
  if (EPI == 0) {
    union { ushort u4[4]; ushort4 v4; } pk;
    float z[4] = {s.x + bb.x, s.y + bb.y, s.z + bb.z, s.w + bb.w};
#pragma unroll
    for (int j = 0; j < 4; ++j) {
      __hip_bfloat16 h = __float2bfloat16(0.5f * z[j] * (1.0f + erff(z[j] * 0.70710678118654752f)));
      pk.u4[j] = *(const ushort*)&h;
    }
    *(ushort4*)(Hout + (size_t)grow * H_DIM + c) = pk.v4;
  } else {
    const int rid = rowid[grow];
    if (rid >= 0) {
      const size_t o = (size_t)rid * H_DIM + c;
      const float4 rv = *(const float4*)(resid + o);
      float4 ov;
      ov.x = rv.x + s.x + bb.x; ov.y = rv.y + s.y + bb.y;
      ov.z = rv.z + s.z + bb.z; ov.w = rv.w + s.w + bb.w;
      *(float4*)(Out + o) = ov;
    }
  }
}

// ---------------------------------------------------------------------------
extern "C" void kernel_launch(void* const* d_in, const int* in_sizes, int n_in,
                              void* d_out, int out_size, void* d_ws, size_t ws_size,
                              hipStream_t stream) {
  const float* hidden = (const float*)d_in[0];
  const int*   tt     = (const int*)d_in[1];
  const float* gamma  = (const float*)d_in[2];
  const float* beta   = (const float*)d_in[3];
  const float* tw1    = (const float*)d_in[4];
  const float* tb1    = (const float*)d_in[5];
  const float* tw2    = (const float*)d_in[6];
  const float* tb2    = (const float*)d_in[7];
  const float* iw1    = (const float*)d_in[8];
  const float* ib1    = (const float*)d_in[9];
  const float* iw2    = (const float*)d_in[10];
  const float* ib2    = (const float*)d_in[11];
  float* out = (float*)d_out;

  const int T = in_sizes[1];          // 8192 tokens
  const int K = H_DIM;
  const int maxrows = FULLROWS + TAILROWS;   // 8704

  char* ws = (char*)d_ws;
  int* ctrl  = (int*)(ws);
  int* pos   = (int*)(ws + 4096);
  int* rowid = (int*)(ws + 65536);
  const size_t WOFF = 131072;
  const size_t WSZ = (size_t)K * K * sizeof(__hip_bfloat16);
  __hip_bfloat16* wTs0 = (__hip_bfloat16*)(ws + WOFF);
  __hip_bfloat16* wTs1 = (__hip_bfloat16*)(ws + WOFF + WSZ);
  __hip_bfloat16* xg   = (__hip_bfloat16*)(ws + WOFF + 2 * WSZ);
  __hip_bfloat16* hb   = xg + (size_t)maxrows * K;
  float* pp = (float*)(hb + (size_t)maxrows * K);   // 8*512*2048 fp32 = 33.5 MB

  partition_kernel<<<1, 256, 0, stream>>>(tt, T, ctrl, pos, rowid);
  pad_zero_kernel<<<512, 256, 0, stream>>>(ctrl, xg);

  dim3 tg(K / 32, K / 32);
  transpose_to_bf16<<<tg, 256, 0, stream>>>(tw1, wTs0);
  transpose_to_bf16<<<tg, 256, 0, stream>>>(iw1, wTs1);

  ln_scatter_kernel<<<T, 256, 0, stream>>>(hidden, gamma, beta, pos, xg);

  gemmk<0><<<384, 512, 0, stream>>>(xg, wTs0, wTs1, tb1, ib1, ctrl, rowid,
                                    hb, nullptr, nullptr, pp);
  combine_kernel<0><<<1024, 256, 0, stream>>>(pp, tb1, ib1, ctrl, rowid,
                                              hb, nullptr, nullptr);

  transpose_to_bf16<<<tg, 256, 0, stream>>>(tw2, wTs0);
  transpose_to_bf16<<<tg, 256, 0, stream>>>(iw2, wTs1);

  gemmk<1><<<384, 512, 0, stream>>>(hb, wTs0, wTs1, tb2, ib2, ctrl, rowid,
                                    nullptr, hidden, out, pp);
  combine_kernel<1><<<1024, 256, 0, stream>>>(pp, tb2, ib2, ctrl, rowid,
                                              nullptr, hidden, out);
}

// Round 15
// 260.137 us; speedup vs baseline: 1.0558x; 1.0466x over previous
//
#include <hip/hip_runtime.h>
#include <hip/hip_bf16.h>

// ---------------------------------------------------------------------------
// MVoT token processor: out = hidden + MLP_{type}(LN(hidden)), type in {0,1}
// R15 = R12 (measured 267us; gemm 108 = 78 full-round + 30 tail, makespan-
// optimal pairing for these block sizes) + R13's verified pad_zero kernel
// (<1us) replacing the 35.6MB memset (~6us). Nothing else touched.
// ---------------------------------------------------------------------------

#define H_DIM 2048
#define FULLROWS 8192
#define TAILROWS 512

typedef __attribute__((ext_vector_type(8))) short s16x8;   // 8 bf16 (4 VGPRs)
typedef __attribute__((ext_vector_type(4))) float f32x4;   // MFMA accumulator
typedef __attribute__((ext_vector_type(4))) int   i32x4;   // asm ds_read dst

typedef __attribute__((address_space(1))) const unsigned int gu32;
typedef __attribute__((address_space(3))) unsigned int lu32;
typedef __attribute__((address_space(3))) short lds_s;

__device__ __forceinline__ void load_lds16(const void* g, void* l) {
  __builtin_amdgcn_global_load_lds((gu32*)g, (lu32*)l, 16, 0, 0);
}

__device__ __forceinline__ s16x8 asbf(i32x4 v) {
  union { i32x4 i; s16x8 s; } u; u.i = v; return u.s;
}

// ---------------------------------------------------------------------------
// Partition (R2/R12-verified): text first, each group padded to 256 rows.
// ctrl: [0]=Mt [1]=Mt_pad [2]=Mi [3]=Mi_pad [4]=total_rows
// ---------------------------------------------------------------------------
__global__ __launch_bounds__(256) void partition_kernel(
    const int* __restrict__ tt, int T, int* __restrict__ ctrl,
    int* __restrict__ pos, int* __restrict__ rowid) {
  __shared__ int psum[256];
  const int tid = threadIdx.x;
  const int npt = T >> 8;
  const int base = tid * npt;
  int cnt = 0;
  for (int i = 0; i < npt; ++i) cnt += (tt[base + i] == 0);
  psum[tid] = cnt;
  __syncthreads();
  for (int off = 1; off < 256; off <<= 1) {
    int v = psum[tid];
    int add = (tid >= off) ? psum[tid - off] : 0;
    __syncthreads();
    psum[tid] = v + add;
    __syncthreads();
  }
  const int Mt = psum[255];
  const int Mt_pad = (Mt + 255) & ~255;
  int tpos = psum[tid] - cnt;
  int ipos = base - tpos;
  for (int i = 0; i < npt; ++i) {
    const int tok = base + i;
    int p;
    if (tt[tok] == 0) p = tpos++;
    else              p = Mt_pad + ipos++;
    pos[tok] = p;
    rowid[p] = tok;
  }
  const int Mi = T - Mt;
  const int Mi_pad = (Mi + 255) & ~255;
  for (int g = Mt + tid; g < Mt_pad; g += 256) rowid[g] = -1;
  for (int g = Mt_pad + Mi + tid; g < Mt_pad + Mi_pad; g += 256) rowid[g] = -1;
  for (int g = Mt_pad + Mi_pad + tid; g < FULLROWS + TAILROWS; g += 256)
    rowid[g] = -1;
  if (tid == 0) {
    ctrl[0] = Mt; ctrl[1] = Mt_pad; ctrl[2] = Mi; ctrl[3] = Mi_pad;
    ctrl[4] = Mt_pad + Mi_pad;
  }
}

// ---------------------------------------------------------------------------
// Zero exactly the xg rows LN doesn't write: [Mt,Mt_pad) u [Mt_pad+Mi, 8704).
// Always exactly 512 rows total. (R13-verified)
// ---------------------------------------------------------------------------
__global__ __launch_bounds__(256) void pad_zero_kernel(
    const int* __restrict__ ctrl, __hip_bfloat16* __restrict__ XG) {
  const int Mt = ctrl[0], Mt_pad = ctrl[1], Mi = ctrl[2];
  const int n1 = Mt_pad - Mt;
  const int start2 = Mt_pad + Mi;
  const int b = blockIdx.x;
  int row;
  if (b < n1) row = Mt + b;
  else {
    const int b2 = b - n1;
    if (start2 + b2 >= FULLROWS + TAILROWS) return;
    row = start2 + b2;
  }
  const int4 z = {0, 0, 0, 0};
  *(int4*)(XG + (size_t)row * H_DIM + threadIdx.x * 8) = z;
}

// ---------------------------------------------------------------------------
// Weight transpose + fp32->bf16: W[k][n] -> WT[n][k] (B^T layout)
// ---------------------------------------------------------------------------
__global__ __launch_bounds__(256) void transpose_to_bf16(
    const float* __restrict__ W, __hip_bfloat16* __restrict__ WT) {
  __shared__ float tile[32][33];
  const int bx = blockIdx.x, by = blockIdx.y;
  const int tid = threadIdx.x;
  const int r = tid >> 3, c4 = (tid & 7) * 4;
  const float4 v = *(const float4*)(W + (size_t)(by * 32 + r) * H_DIM + bx * 32 + c4);
  tile[r][c4 + 0] = v.x; tile[r][c4 + 1] = v.y;
  tile[r][c4 + 2] = v.z; tile[r][c4 + 3] = v.w;
  __syncthreads();
  union { ushort u[4]; ushort4 v4; } pk;
#pragma unroll
  for (int j = 0; j < 4; ++j) {
    __hip_bfloat16 h = __float2bfloat16(tile[c4 + j][r]);
    pk.u[j] = *(const ushort*)&h;
  }
  *(ushort4*)(WT + (size_t)(bx * 32 + r) * H_DIM + by * 32 + c4) = pk.v4;
}

// ---------------------------------------------------------------------------
// LayerNorm (fp32) -> bf16, scatter row to its gathered position.
// ---------------------------------------------------------------------------
__global__ __launch_bounds__(256) void ln_scatter_kernel(
    const float* __restrict__ X, const float* __restrict__ gamma,
    const float* __restrict__ beta, const int* __restrict__ pos,
    __hip_bfloat16* __restrict__ XG) {
  const int t = blockIdx.x, tid = threadIdx.x;
  const float* row = X + (size_t)t * H_DIM;
  float x[8];
  {
    float4 v0 = *(const float4*)(row + tid * 8);
    float4 v1 = *(const float4*)(row + tid * 8 + 4);
    x[0] = v0.x; x[1] = v0.y; x[2] = v0.z; x[3] = v0.w;
    x[4] = v1.x; x[5] = v1.y; x[6] = v1.z; x[7] = v1.w;
  }
  float s = 0.f, q = 0.f;
#pragma unroll
  for (int j = 0; j < 8; ++j) { s += x[j]; q += x[j] * x[j]; }
#pragma unroll
  for (int off = 32; off > 0; off >>= 1) {
    s += __shfl_down(s, off);
    q += __shfl_down(q, off);
  }
  __shared__ float ls[4], lq[4];
  if ((tid & 63) == 0) { ls[tid >> 6] = s; lq[tid >> 6] = q; }
  __syncthreads();
  const float S = ls[0] + ls[1] + ls[2] + ls[3];
  const float Q = lq[0] + lq[1] + lq[2] + lq[3];
  const float mu = S * (1.0f / H_DIM);
  const float var = Q * (1.0f / H_DIM) - mu * mu;
  const float rstd = rsqrtf(var + 1e-12f);
  const int p = pos[t];
  float4 g0 = *(const float4*)(gamma + tid * 8);
  float4 g1 = *(const float4*)(gamma + tid * 8 + 4);
  float4 b0 = *(const float4*)(beta + tid * 8);
  float4 b1 = *(const float4*)(beta + tid * 8 + 4);
  float g[8] = {g0.x, g0.y, g0.z, g0.w, g1.x, g1.y, g1.z, g1.w};
  float b[8] = {b0.x, b0.y, b0.z, b0.w, b1.x, b1.y, b1.z, b1.w};
  union { ushort u[8]; int4 v; } pk;
#pragma unroll
  for (int j = 0; j < 8; ++j) {
    float y = (x[j] - mu) * rstd * g[j] + b[j];
    __hip_bfloat16 h = __float2bfloat16(y);
    pk.u[j] = *(const ushort*)&h;
  }
  *(int4*)(XG + (size_t)p * H_DIM + tid * 8) = pk.v;
}

// --- asm helpers -----------------------------------------------------------
#define DSRD(dst, addr, OFF) \
  asm volatile("ds_read_b128 %0, %1 offset:" OFF : "=v"(dst) : "v"(addr))
#define PBAR asm volatile("s_barrier" ::: "memory")
#define SB0  __builtin_amdgcn_sched_barrier(0)
#define LGKM0 do { \
  asm volatile("s_waitcnt lgkmcnt(0)" ::: "memory"); SB0; } while (0)
#define VM0 asm volatile("s_waitcnt vmcnt(0)" ::: "memory")

__device__ __forceinline__ float gelu_exact(float z) {
  return 0.5f * z * (1.0f + erff(z * 0.70710678118654752f));
}

// ---------------------------------------------------------------------------
// Unified GEMM (R12-verbatim), grid = 384 x 512 thr:
//  bid < 256: FULL path (R4-verified): 256x256 tile, BK=64, 8 waves of
//    128x64 (acc[8][4]), 4 asm phases/K-tile, vmcnt(4), XOR-swizzled LDS.
//  bid >= 256: TAIL path (R11-verified loop): 128x256 tile, BK=32,
//    K-range = kp*512..+512 (kp=tb&3, 16 inner tiles), rows 8192..8703,
//    fp32 partials to pp[kp][512][2048]. 128 tail blocks pair one-per-CU
//    behind the full round (makespan 78+30 = 108, measured).
// ---------------------------------------------------------------------------
template <int EPI>
__global__ __launch_bounds__(512, 2) void gemmk(
    const __hip_bfloat16* __restrict__ A,
    const __hip_bfloat16* __restrict__ WTt, const __hip_bfloat16* __restrict__ WTi,
    const float* __restrict__ bt, const float* __restrict__ bi,
    const int* __restrict__ ctrl, const int* __restrict__ rowid,
    __hip_bfloat16* __restrict__ Hout,
    const float* __restrict__ resid, float* __restrict__ Out,
    float* __restrict__ pp) {
  constexpr int K = H_DIM;
  const int Mt_pad = ctrl[1];

  __shared__ __align__(16) char smem[131072];
  const unsigned sBase = (unsigned)(uintptr_t)(lds_s*)smem;

  const int tid = threadIdx.x;
  const int w = tid >> 6, l = tid & 63;
  const int bid = blockIdx.x;

  const int srow8 = l >> 3;
  const int sg = (l & 7) ^ srow8;
  const int r16 = l & 15;
  const int r4base = (l >> 4) * 4;
  const int hl = (l & 15) >> 1;
  const int gr = (((l & 1) << 2) | (l >> 4)) ^ hl;

  if (bid < 256) {
    // ===================== FULL PATH (R4/R12 verbatim) ====================
    constexpr int NT = K / 64;          // 32 K-tiles
    const int m0 = (bid >> 3) * 256;
    const int n0 = (bid & 7) * 256;
    const bool is_text = (m0 < Mt_pad);
    const short* Ag = (const short*)A;
    const short* Bg = (const short*)(is_text ? WTt : WTi);
    const float* bias = is_text ? bt : bi;

    const int wm = w >> 2, wn = w & 3;
    const int scol8 = sg * 8;

    auto stageA = [&](int bI, int h, int kk) {
#pragma unroll
      for (int c = 0; c < 2; ++c) {
        const short* src = Ag + (size_t)(m0 + h * 128 + c * 64 + w * 8 + srow8) * K + kk + scol8;
        load_lds16(src, smem + bI * 32768 + h * 16384 + (c * 4096 + w * 512) * 2);
      }
    };
    auto stageB = [&](int bI, int h, int kk) {
#pragma unroll
      for (int c = 0; c < 2; ++c) {
        const short* src = Bg + (size_t)(n0 + h * 128 + c * 64 + w * 8 + srow8) * K + kk + scol8;
        load_lds16(src, smem + 65536 + bI * 32768 + h * 16384 + (c * 4096 + w * 512) * 2);
      }
    };

    int off2[2];
#pragma unroll
    for (int ks = 0; ks < 2; ++ks)
      off2[ks] = r16 * 64 + (((ks * 4 + (l >> 4)) ^ (l & 7)) * 8);

    unsigned ardA[2][2], ardB[2][2];
#pragma unroll
    for (int bI = 0; bI < 2; ++bI)
#pragma unroll
      for (int ks = 0; ks < 2; ++ks) {
        ardA[bI][ks] = sBase + bI * 32768u + (unsigned)(wm * 16384 + off2[ks] * 2);
        ardB[bI][ks] = sBase + 65536u + bI * 32768u +
                       (unsigned)((wn >> 1) * 16384 + ((wn & 1) * 4096 + off2[ks]) * 2);
      }

    i32x4 a[4][2], b[4][2];
    f32x4 acc[8][4];
    const f32x4 zero = {0.f, 0.f, 0.f, 0.f};
#pragma unroll
    for (int i = 0; i < 8; ++i)
#pragma unroll
      for (int j = 0; j < 4; ++j) acc[i][j] = zero;

    auto mfmaQ = [&](int fmBase, int fnBase) {
#pragma unroll
      for (int fm = 0; fm < 4; ++fm)
#pragma unroll
        for (int fn = 0; fn < 2; ++fn)
#pragma unroll
          for (int ks = 0; ks < 2; ++ks)
            acc[fmBase + fm][fnBase + fn] = __builtin_amdgcn_mfma_f32_16x16x32_bf16(
                asbf(a[fm][ks]), asbf(b[fnBase + fn][ks]),
                acc[fmBase + fm][fnBase + fn], 0, 0, 0);
    };

#define TILE(C) do {                                                          \
    DSRD(a[0][0], ardA[C][0], "0");     DSRD(a[0][1], ardA[C][1], "0");       \
    DSRD(a[1][0], ardA[C][0], "2048");  DSRD(a[1][1], ardA[C][1], "2048");    \
    DSRD(a[2][0], ardA[C][0], "4096");  DSRD(a[2][1], ardA[C][1], "4096");    \
    DSRD(a[3][0], ardA[C][0], "6144");  DSRD(a[3][1], ardA[C][1], "6144");    \
    DSRD(b[0][0], ardB[C][0], "0");     DSRD(b[0][1], ardB[C][1], "0");       \
    DSRD(b[1][0], ardB[C][0], "2048");  DSRD(b[1][1], ardB[C][1], "2048");    \
    stageA(C ^ 1, 0, _kA);                                                    \
    PBAR; LGKM0;                                                              \
    __builtin_amdgcn_s_setprio(1); mfmaQ(0, 0); __builtin_amdgcn_s_setprio(0);\
    SB0; PBAR;                                                                \
    DSRD(b[2][0], ardB[C][0], "4096");  DSRD(b[2][1], ardB[C][1], "4096");    \
    DSRD(b[3][0], ardB[C][0], "6144");  DSRD(b[3][1], ardB[C][1], "6144");    \
    stageA(C ^ 1, 1, _kA);                                                    \
    PBAR; LGKM0;                                                              \
    __builtin_amdgcn_s_setprio(1); mfmaQ(0, 2); __builtin_amdgcn_s_setprio(0);\
    SB0; PBAR;                                                                \
    DSRD(a[0][0], ardA[C][0], "8192");  DSRD(a[0][1], ardA[C][1], "8192");    \
    DSRD(a[1][0], ardA[C][0], "10240"); DSRD(a[1][1], ardA[C][1], "10240");   \
    DSRD(a[2][0], ardA[C][0], "12288"); DSRD(a[2][1], ardA[C][1], "12288");   \
    DSRD(a[3][0], ardA[C][0], "14336"); DSRD(a[3][1], ardA[C][1], "14336");   \
    stageB(C, 0, _kB);                                                        \
    PBAR; LGKM0;                                                              \
    __builtin_amdgcn_s_setprio(1); mfmaQ(4, 2); __builtin_amdgcn_s_setprio(0);\
    SB0; PBAR;                                                                \
    stageB(C, 1, _kB);                                                        \
    asm volatile("s_waitcnt vmcnt(4)" ::: "memory");                          \
    PBAR; SB0;                                                                \
    __builtin_amdgcn_s_setprio(1); mfmaQ(4, 0); __builtin_amdgcn_s_setprio(0);\
    SB0; PBAR;                                                                \
  } while (0)

    stageA(0, 0, 0); stageA(0, 1, 0);
    stageB(0, 0, 0); stageB(0, 1, 0);
    stageB(1, 0, 64); stageB(1, 1, 64);
    asm volatile("s_waitcnt vmcnt(4)" ::: "memory");
    PBAR;

    int _kA, _kB;
    for (int t = 0; t < NT; t += 2) {
      _kA = (t + 1 < NT ? t + 1 : NT - 1) * 64;
      _kB = (t + 2 < NT ? t + 2 : NT - 1) * 64;
      TILE(0);
      _kA = (t + 2 < NT ? t + 2 : NT - 1) * 64;
      _kB = (t + 3 < NT ? t + 3 : NT - 1) * 64;
      TILE(1);
    }
#undef TILE
    asm volatile("s_waitcnt vmcnt(0) lgkmcnt(0)" ::: "memory");

    float bb[4];
#pragma unroll
    for (int fn = 0; fn < 4; ++fn) bb[fn] = bias[n0 + wn * 64 + fn * 16 + r16];
    if (EPI == 0) {
#pragma unroll
      for (int fm = 0; fm < 8; ++fm) {
        const int grow = m0 + wm * 128 + fm * 16 + r4base;
#pragma unroll
        for (int fn = 0; fn < 4; ++fn) {
          const int gcol = n0 + wn * 64 + fn * 16 + r16;
          f32x4 v = acc[fm][fn];
#pragma unroll
          for (int i = 0; i < 4; ++i)
            Hout[(size_t)(grow + i) * K + gcol] = __float2bfloat16(gelu_exact(v[i] + bb[fn]));
        }
      }
    } else {
#pragma unroll
      for (int fm = 0; fm < 8; ++fm) {
        const int grow = m0 + wm * 128 + fm * 16 + r4base;
        int rid[4];
#pragma unroll
        for (int i = 0; i < 4; ++i) rid[i] = rowid[grow + i];
#pragma unroll
        for (int fn = 0; fn < 4; ++fn) {
          const int gcol = n0 + wn * 64 + fn * 16 + r16;
          f32x4 v = acc[fm][fn];
#pragma unroll
          for (int i = 0; i < 4; ++i) {
            if (rid[i] >= 0) {
              const size_t o = (size_t)rid[i] * K + gcol;
              Out[o] = resid[o] + v[i] + bb[fn];
            }
          }
        }
      }
    }
  } else {
    // ============== TAIL PATH (R11/R12 verbatim, KSPLIT=4) ================
    const int tb = bid - 256;           // 0..127
    const int kp = tb & 3;
    const int n0 = ((tb >> 2) & 7) * 256;
    const int m0 = FULLROWS + (tb >> 5) * 128;
    const int kk0 = kp * 512;           // K range [kk0, kk0+512), 16 K-tiles
    const bool is_text = (m0 < Mt_pad);
    const short* Ag = (const short*)A;
    const short* Bg = (const short*)(is_text ? WTt : WTi);

    const int wm = w >> 2, wn = w & 3;
    const int sRowAdj = sg >> 2;
    const int sKAdj = (sg & 3) * 8;

    auto stageA = [&](int bI, int kk) {
      const int mr = w * 8 + srow8;
      const short* src = Ag + (size_t)(m0 + mr * 2 + sRowAdj) * K + kk + sKAdj;
      load_lds16(src, smem + bI * 8192 + w * 1024);
    };
    auto stageB = [&](int bI, int c2, int kk) {
      const int mr = c2 * 64 + w * 8 + srow8;
      const short* src = Bg + (size_t)(n0 + mr * 2 + sRowAdj) * K + kk + sKAdj;
      load_lds16(src, smem + 16384 + bI * 16384 + c2 * 8192 + w * 1024);
    };

    unsigned ardA[2], ardB[2];
#pragma unroll
    for (int bI = 0; bI < 2; ++bI) {
      ardA[bI] = sBase + bI * 8192u + (unsigned)(wm * 4096 + hl * 128 + gr * 16);
      ardB[bI] = sBase + 16384u + bI * 16384u + (unsigned)(wn * 4096 + hl * 128 + gr * 16);
    }

    i32x4 a[4], b[4];
    f32x4 acc[4][4];
    const f32x4 zero = {0.f, 0.f, 0.f, 0.f};
#pragma unroll
    for (int i = 0; i < 4; ++i)
#pragma unroll
      for (int j = 0; j < 4; ++j) acc[i][j] = zero;

#define RD_TILE(C) do {                                                   \
    DSRD(a[0], ardA[C], "0");    DSRD(a[1], ardA[C], "1024");             \
    DSRD(a[2], ardA[C], "2048"); DSRD(a[3], ardA[C], "3072");             \
    DSRD(b[0], ardB[C], "0");    DSRD(b[1], ardB[C], "1024");             \
    DSRD(b[2], ardB[C], "2048"); DSRD(b[3], ardB[C], "3072");             \
  } while (0)

    stageA(0, kk0);
    stageB(0, 0, kk0); stageB(0, 1, kk0);
    VM0;
    PBAR;

    for (int i = 0; i < 16; ++i) {
      const int c = i & 1;
      const int kn = kk0 + (i + 1 < 16 ? i + 1 : 15) * 32;
      stageA(c ^ 1, kn);
      stageB(c ^ 1, 0, kn); stageB(c ^ 1, 1, kn);
      RD_TILE(c);
      LGKM0;
      __builtin_amdgcn_s_setprio(1);
#pragma unroll
      for (int f = 0; f < 4; ++f)
#pragma unroll
        for (int fn = 0; fn < 4; ++fn)
          acc[f][fn] = __builtin_amdgcn_mfma_f32_16x16x32_bf16(
              asbf(a[f]), asbf(b[fn]), acc[f][fn], 0, 0, 0);
      __builtin_amdgcn_s_setprio(0);
      SB0;
      VM0;
      PBAR;
    }
#undef RD_TILE
    asm volatile("s_waitcnt vmcnt(0) lgkmcnt(0)" ::: "memory");

    // raw fp32 partial write: pp[kp][512][2048]
    float* ppk = pp + (size_t)kp * TAILROWS * H_DIM;
    const int mrel = m0 - FULLROWS;
#pragma unroll
    for (int fm = 0; fm < 4; ++fm) {
      const int prow = mrel + wm * 64 + fm * 16 + r4base;
#pragma unroll
      for (int fn = 0; fn < 4; ++fn) {
        const int gcol = n0 + wn * 64 + fn * 16 + r16;
        f32x4 v = acc[fm][fn];
#pragma unroll
        for (int i = 0; i < 4; ++i)
          ppk[(size_t)(prow + i) * H_DIM + gcol] = v[i];
      }
    }
  }
}

// ---------------------------------------------------------------------------
// Combine: sum 4 K-partials for tail rows 8192..8703, apply epilogue.
// ---------------------------------------------------------------------------
template <int EPI>
__global__ __launch_bounds__(256) void combine_kernel(
    const float* __restrict__ pp, const float* __restrict__ bt,
    const float* __restrict__ bi, const int* __restrict__ ctrl,
    const int* __restrict__ rowid, __hip_bfloat16* __restrict__ Hout,
    const float* __restrict__ resid, float* __restrict__ Out) {
  const int u = blockIdx.x * 256 + threadIdx.x;      // 0..262143
  const int r = u >> 9;                              // 0..511
  const int c = (u & 511) * 4;
  const size_t off = (size_t)r * H_DIM + c;
  float4 s = *(const float4*)(pp + off);
  const float4 s1 = *(const float4*)(pp + (size_t)TAILROWS * H_DIM + off);
  const float4 s2 = *(const float4*)(pp + (size_t)2 * TAILROWS * H_DIM + off);
  const float4 s3 = *(const float4*)(pp + (size_t)3 * TAILROWS * H_DIM + off);
  s.x += s1.x + s2.x + s3.x; s.y += s1.y + s2.y + s3.y;
  s.z += s1.z + s2.z + s3.z; s.w += s1.w + s2.w + s3.w;
  const int grow = FULLROWS + r;
  const float* bias = (grow < ctrl[1]) ? bt : bi;
  const float4 bb = *(const float4*)(bias + c);
  if (EPI == 0) {
    union { ushort u4[4]; ushort4 v4; } pk;
    float z[4] = {s.x + bb.x, s.y + bb.y, s.z + bb.z, s.w + bb.w};
#pragma unroll
    for (int j = 0; j < 4; ++j) {
      __hip_bfloat16 h = __float2bfloat16(0.5f * z[j] * (1.0f + erff(z[j] * 0.70710678118654752f)));
      pk.u4[j] = *(const ushort*)&h;
    }
    *(ushort4*)(Hout + (size_t)grow * H_DIM + c) = pk.v4;
  } else {
    const int rid = rowid[grow];
    if (rid >= 0) {
      const size_t o = (size_t)rid * H_DIM + c;
      const float4 rv = *(const float4*)(resid + o);
      float4 ov;
      ov.x = rv.x + s.x + bb.x; ov.y = rv.y + s.y + bb.y;
      ov.z = rv.z + s.z + bb.z; ov.w = rv.w + s.w + bb.w;
      *(float4*)(Out + o) = ov;
    }
  }
}

// ---------------------------------------------------------------------------
extern "C" void kernel_launch(void* const* d_in, const int* in_sizes, int n_in,
                              void* d_out, int out_size, void* d_ws, size_t ws_size,
                              hipStream_t stream) {
  const float* hidden = (const float*)d_in[0];
  const int*   tt     = (const int*)d_in[1];
  const float* gamma  = (const float*)d_in[2];
  const float* beta   = (const float*)d_in[3];
  const float* tw1    = (const float*)d_in[4];
  const float* tb1    = (const float*)d_in[5];
  const float* tw2    = (const float*)d_in[6];
  const float* tb2    = (const float*)d_in[7];
  const float* iw1    = (const float*)d_in[8];
  const float* ib1    = (const float*)d_in[9];
  const float* iw2    = (const float*)d_in[10];
  const float* ib2    = (const float*)d_in[11];
  float* out = (float*)d_out;

  const int T = in_sizes[1];          // 8192 tokens
  const int K = H_DIM;
  const int maxrows = FULLROWS + TAILROWS;   // 8704

  char* ws = (char*)d_ws;
  int* ctrl  = (int*)(ws);
  int* pos   = (int*)(ws + 4096);
  int* rowid = (int*)(ws + 65536);
  const size_t WOFF = 131072;
  const size_t WSZ = (size_t)K * K * sizeof(__hip_bfloat16);
  __hip_bfloat16* tw1T = (__hip_bfloat16*)(ws + WOFF);
  __hip_bfloat16* tw2T = (__hip_bfloat16*)(ws + WOFF + WSZ);
  __hip_bfloat16* iw1T = (__hip_bfloat16*)(ws + WOFF + 2 * WSZ);
  __hip_bfloat16* iw2T = (__hip_bfloat16*)(ws + WOFF + 3 * WSZ);
  __hip_bfloat16* xg   = (__hip_bfloat16*)(ws + WOFF + 4 * WSZ);
  __hip_bfloat16* hb   = xg + (size_t)maxrows * K;
  float* pp = (float*)(hb + (size_t)maxrows * K);   // 4*512*2048 fp32 = 16.8 MB

  partition_kernel<<<1, 256, 0, stream>>>(tt, T, ctrl, pos, rowid);
  pad_zero_kernel<<<512, 256, 0, stream>>>(ctrl, xg);

  dim3 tg(K / 32, K / 32);
  transpose_to_bf16<<<tg, 256, 0, stream>>>(tw1, tw1T);
  transpose_to_bf16<<<tg, 256, 0, stream>>>(tw2, tw2T);
  transpose_to_bf16<<<tg, 256, 0, stream>>>(iw1, iw1T);
  transpose_to_bf16<<<tg, 256, 0, stream>>>(iw2, iw2T);

  ln_scatter_kernel<<<T, 256, 0, stream>>>(hidden, gamma, beta, pos, xg);

  gemmk<0><<<384, 512, 0, stream>>>(xg, tw1T, iw1T, tb1, ib1, ctrl, rowid,
                                    hb, nullptr, nullptr, pp);
  combine_kernel<0><<<1024, 256, 0, stream>>>(pp, tb1, ib1, ctrl, rowid,
                                              hb, nullptr, nullptr);
  gemmk<1><<<384, 512, 0, stream>>>(hb, tw2T, iw2T, tb2, ib2, ctrl, rowid,
                                    nullptr, hidden, out, pp);
  combine_kernel<1><<<1024, 256, 0, stream>>>(pp, tb2, ib2, ctrl, rowid,
                                              nullptr, hidden, out);
}

// Round 16
// 254.599 us; speedup vs baseline: 1.0788x; 1.0218x over previous
//
#include <hip/hip_runtime.h>
#include <hip/hip_bf16.h>

// ---------------------------------------------------------------------------
// MVoT token processor: out = hidden + MLP_{type}(LN(hidden)), type in {0,1}
// R16 = R15 (260us) with the full-path TILE macro reduced from 8 barriers to
// 4 per K-tile (audited single-barrier phases; P3's stageB moved after the
// barrier to preserve the read-retire-before-overwrite guarantee; Q4 now
// overlaps the vmcnt drain), and the 4 weight transposes fused into 1 launch.
// ---------------------------------------------------------------------------

#define H_DIM 2048
#define FULLROWS 8192
#define TAILROWS 512

typedef __attribute__((ext_vector_type(8))) short s16x8;   // 8 bf16 (4 VGPRs)
typedef __attribute__((ext_vector_type(4))) float f32x4;   // MFMA accumulator
typedef __attribute__((ext_vector_type(4))) int   i32x4;   // asm ds_read dst

typedef __attribute__((address_space(1))) const unsigned int gu32;
typedef __attribute__((address_space(3))) unsigned int lu32;
typedef __attribute__((address_space(3))) short lds_s;

__device__ __forceinline__ void load_lds16(const void* g, void* l) {
  __builtin_amdgcn_global_load_lds((gu32*)g, (lu32*)l, 16, 0, 0);
}

__device__ __forceinline__ s16x8 asbf(i32x4 v) {
  union { i32x4 i; s16x8 s; } u; u.i = v; return u.s;
}

// ---------------------------------------------------------------------------
// Partition (R2/R12-verified): text first, each group padded to 256 rows.
// ctrl: [0]=Mt [1]=Mt_pad [2]=Mi [3]=Mi_pad [4]=total_rows
// ---------------------------------------------------------------------------
__global__ __launch_bounds__(256) void partition_kernel(
    const int* __restrict__ tt, int T, int* __restrict__ ctrl,
    int* __restrict__ pos, int* __restrict__ rowid) {
  __shared__ int psum[256];
  const int tid = threadIdx.x;
  const int npt = T >> 8;
  const int base = tid * npt;
  int cnt = 0;
  for (int i = 0; i < npt; ++i) cnt += (tt[base + i] == 0);
  psum[tid] = cnt;
  __syncthreads();
  for (int off = 1; off < 256; off <<= 1) {
    int v = psum[tid];
    int add = (tid >= off) ? psum[tid - off] : 0;
    __syncthreads();
    psum[tid] = v + add;
    __syncthreads();
  }
  const int Mt = psum[255];
  const int Mt_pad = (Mt + 255) & ~255;
  int tpos = psum[tid] - cnt;
  int ipos = base - tpos;
  for (int i = 0; i < npt; ++i) {
    const int tok = base + i;
    int p;
    if (tt[tok] == 0) p = tpos++;
    else              p = Mt_pad + ipos++;
    pos[tok] = p;
    rowid[p] = tok;
  }
  const int Mi = T - Mt;
  const int Mi_pad = (Mi + 255) & ~255;
  for (int g = Mt + tid; g < Mt_pad; g += 256) rowid[g] = -1;
  for (int g = Mt_pad + Mi + tid; g < Mt_pad + Mi_pad; g += 256) rowid[g] = -1;
  for (int g = Mt_pad + Mi_pad + tid; g < FULLROWS + TAILROWS; g += 256)
    rowid[g] = -1;
  if (tid == 0) {
    ctrl[0] = Mt; ctrl[1] = Mt_pad; ctrl[2] = Mi; ctrl[3] = Mi_pad;
    ctrl[4] = Mt_pad + Mi_pad;
  }
}

// ---------------------------------------------------------------------------
// Zero exactly the xg rows LN doesn't write (R13/R15-verified).
// ---------------------------------------------------------------------------
__global__ __launch_bounds__(256) void pad_zero_kernel(
    const int* __restrict__ ctrl, __hip_bfloat16* __restrict__ XG) {
  const int Mt = ctrl[0], Mt_pad = ctrl[1], Mi = ctrl[2];
  const int n1 = Mt_pad - Mt;
  const int start2 = Mt_pad + Mi;
  const int b = blockIdx.x;
  int row;
  if (b < n1) row = Mt + b;
  else {
    const int b2 = b - n1;
    if (start2 + b2 >= FULLROWS + TAILROWS) return;
    row = start2 + b2;
  }
  const int4 z = {0, 0, 0, 0};
  *(int4*)(XG + (size_t)row * H_DIM + threadIdx.x * 8) = z;
}

// ---------------------------------------------------------------------------
// Fused weight transpose + fp32->bf16 for all 4 matrices (grid.z selects).
// ---------------------------------------------------------------------------
__global__ __launch_bounds__(256) void transpose_to_bf16_x4(
    const float* __restrict__ W0, const float* __restrict__ W1,
    const float* __restrict__ W2, const float* __restrict__ W3,
    __hip_bfloat16* __restrict__ O0, __hip_bfloat16* __restrict__ O1,
    __hip_bfloat16* __restrict__ O2, __hip_bfloat16* __restrict__ O3) {
  __shared__ float tile[32][33];
  const int bx = blockIdx.x, by = blockIdx.y, bz = blockIdx.z;
  const float* W = (bz == 0) ? W0 : (bz == 1) ? W1 : (bz == 2) ? W2 : W3;
  __hip_bfloat16* WT = (bz == 0) ? O0 : (bz == 1) ? O1 : (bz == 2) ? O2 : O3;
  const int tid = threadIdx.x;
  const int r = tid >> 3, c4 = (tid & 7) * 4;
  const float4 v = *(const float4*)(W + (size_t)(by * 32 + r) * H_DIM + bx * 32 + c4);
  tile[r][c4 + 0] = v.x; tile[r][c4 + 1] = v.y;
  tile[r][c4 + 2] = v.z; tile[r][c4 + 3] = v.w;
  __syncthreads();
  union { ushort u[4]; ushort4 v4; } pk;
#pragma unroll
  for (int j = 0; j < 4; ++j) {
    __hip_bfloat16 h = __float2bfloat16(tile[c4 + j][r]);
    pk.u[j] = *(const ushort*)&h;
  }
  *(ushort4*)(WT + (size_t)(bx * 32 + r) * H_DIM + by * 32 + c4) = pk.v4;
}

// ---------------------------------------------------------------------------
// LayerNorm (fp32) -> bf16, scatter row to its gathered position.
// ---------------------------------------------------------------------------
__global__ __launch_bounds__(256) void ln_scatter_kernel(
    const float* __restrict__ X, const float* __restrict__ gamma,
    const float* __restrict__ beta, const int* __restrict__ pos,
    __hip_bfloat16* __restrict__ XG) {
  const int t = blockIdx.x, tid = threadIdx.x;
  const float* row = X + (size_t)t * H_DIM;
  float x[8];
  {
    float4 v0 = *(const float4*)(row + tid * 8);
    float4 v1 = *(const float4*)(row + tid * 8 + 4);
    x[0] = v0.x; x[1] = v0.y; x[2] = v0.z; x[3] = v0.w;
    x[4] = v1.x; x[5] = v1.y; x[6] = v1.z; x[7] = v1.w;
  }
  float s = 0.f, q = 0.f;
#pragma unroll
  for (int j = 0; j < 8; ++j) { s += x[j]; q += x[j] * x[j]; }
#pragma unroll
  for (int off = 32; off > 0; off >>= 1) {
    s += __shfl_down(s, off);
    q += __shfl_down(q, off);
  }
  __shared__ float ls[4], lq[4];
  if ((tid & 63) == 0) { ls[tid >> 6] = s; lq[tid >> 6] = q; }
  __syncthreads();
  const float S = ls[0] + ls[1] + ls[2] + ls[3];
  const float Q = lq[0] + lq[1] + lq[2] + lq[3];
  const float mu = S * (1.0f / H_DIM);
  const float var = Q * (1.0f / H_DIM) - mu * mu;
  const float rstd = rsqrtf(var + 1e-12f);
  const int p = pos[t];
  float4 g0 = *(const float4*)(gamma + tid * 8);
  float4 g1 = *(const float4*)(gamma + tid * 8 + 4);
  float4 b0 = *(const float4*)(beta + tid * 8);
  float4 b1 = *(const float4*)(beta + tid * 8 + 4);
  float g[8] = {g0.x, g0.y, g0.z, g0.w, g1.x, g1.y, g1.z, g1.w};
  float b[8] = {b0.x, b0.y, b0.z, b0.w, b1.x, b1.y, b1.z, b1.w};
  union { ushort u[8]; int4 v; } pk;
#pragma unroll
  for (int j = 0; j < 8; ++j) {
    float y = (x[j] - mu) * rstd * g[j] + b[j];
    __hip_bfloat16 h = __float2bfloat16(y);
    pk.u[j] = *(const ushort*)&h;
  }
  *(int4*)(XG + (size_t)p * H_DIM + tid * 8) = pk.v;
}

// --- asm helpers -----------------------------------------------------------
#define DSRD(dst, addr, OFF) \
  asm volatile("ds_read_b128 %0, %1 offset:" OFF : "=v"(dst) : "v"(addr))
#define PBAR asm volatile("s_barrier" ::: "memory")
#define SB0  __builtin_amdgcn_sched_barrier(0)
#define LGKM0 do { \
  asm volatile("s_waitcnt lgkmcnt(0)" ::: "memory"); SB0; } while (0)
#define VM0 asm volatile("s_waitcnt vmcnt(0)" ::: "memory")

__device__ __forceinline__ float gelu_exact(float z) {
  return 0.5f * z * (1.0f + erff(z * 0.70710678118654752f));
}

// ---------------------------------------------------------------------------
// Unified GEMM, grid = 384 x 512 thr:
//  bid < 256: FULL path, single-barrier 4-phase TILE (4 barriers/K-tile):
//   P1: rd a_lo(8)+b_lo(4); stageA(h0) | PBAR | lgkm0 | Q1
//   P2: rd b_hi(4);         stageA(h1) | PBAR | lgkm0 | Q2
//   P3: rd a_hi(8)                     | PBAR | lgkm0 | stageB(h0) | Q3
//       (stageB AFTER the barrier: its target B(t)h0 was read at P2 by
//        wn0/1 waves, whose lgkm0_P2 precedes their PBAR_P3 arrival)
//   P4: stageB(h1) | Q4 (reg-only, no waits) | vmcnt(4) | PBAR
//   vmcnt(4)@P4: 12 outstanding -> drains B(t+1)+A(t+1), leaves B(t+2).
//   All other stage targets are >=2 phases after their last read (audited
//   under <=1-phase drift).
//  bid >= 256: TAIL path (R11/R12/R15-verbatim, KSPLIT=4).
// ---------------------------------------------------------------------------
template <int EPI>
__global__ __launch_bounds__(512, 2) void gemmk(
    const __hip_bfloat16* __restrict__ A,
    const __hip_bfloat16* __restrict__ WTt, const __hip_bfloat16* __restrict__ WTi,
    const float* __restrict__ bt, const float* __restrict__ bi,
    const int* __restrict__ ctrl, const int* __restrict__ rowid,
    __hip_bfloat16* __restrict__ Hout,
    const float* __restrict__ resid, float* __restrict__ Out,
    float* __restrict__ pp) {
  constexpr int K = H_DIM;
  const int Mt_pad = ctrl[1];

  __shared__ __align__(16) char smem[131072];
  const unsigned sBase = (unsigned)(uintptr_t)(lds_s*)smem;

  const int tid = threadIdx.x;
  const int w = tid >> 6, l = tid & 63;
  const int bid = blockIdx.x;

  const int srow8 = l >> 3;
  const int sg = (l & 7) ^ srow8;
  const int r16 = l & 15;
  const int r4base = (l >> 4) * 4;
  const int hl = (l & 15) >> 1;
  const int gr = (((l & 1) << 2) | (l >> 4)) ^ hl;

  if (bid < 256) {
    // ===================== FULL PATH (4-barrier TILE) =====================
    constexpr int NT = K / 64;          // 32 K-tiles
    const int m0 = (bid >> 3) * 256;
    const int n0 = (bid & 7) * 256;
    const bool is_text = (m0 < Mt_pad);
    const short* Ag = (const short*)A;
    const short* Bg = (const short*)(is_text ? WTt : WTi);
    const float* bias = is_text ? bt : bi;

    const int wm = w >> 2, wn = w & 3;
    const int scol8 = sg * 8;

    auto stageA = [&](int bI, int h, int kk) {
#pragma unroll
      for (int c = 0; c < 2; ++c) {
        const short* src = Ag + (size_t)(m0 + h * 128 + c * 64 + w * 8 + srow8) * K + kk + scol8;
        load_lds16(src, smem + bI * 32768 + h * 16384 + (c * 4096 + w * 512) * 2);
      }
    };
    auto stageB = [&](int bI, int h, int kk) {
#pragma unroll
      for (int c = 0; c < 2; ++c) {
        const short* src = Bg + (size_t)(n0 + h * 128 + c * 64 + w * 8 + srow8) * K + kk + scol8;
        load_lds16(src, smem + 65536 + bI * 32768 + h * 16384 + (c * 4096 + w * 512) * 2);
      }
    };

    int off2[2];
#pragma unroll
    for (int ks = 0; ks < 2; ++ks)
      off2[ks] = r16 * 64 + (((ks * 4 + (l >> 4)) ^ (l & 7)) * 8);

    unsigned ardA[2][2], ardB[2][2];
#pragma unroll
    for (int bI = 0; bI < 2; ++bI)
#pragma unroll
      for (int ks = 0; ks < 2; ++ks) {
        ardA[bI][ks] = sBase + bI * 32768u + (unsigned)(wm * 16384 + off2[ks] * 2);
        ardB[bI][ks] = sBase + 65536u + bI * 32768u +
                       (unsigned)((wn >> 1) * 16384 + ((wn & 1) * 4096 + off2[ks]) * 2);
      }

    i32x4 a[4][2], b[4][2];
    f32x4 acc[8][4];
    const f32x4 zero = {0.f, 0.f, 0.f, 0.f};
#pragma unroll
    for (int i = 0; i < 8; ++i)
#pragma unroll
      for (int j = 0; j < 4; ++j) acc[i][j] = zero;

    auto mfmaQ = [&](int fmBase, int fnBase) {
#pragma unroll
      for (int fm = 0; fm < 4; ++fm)
#pragma unroll
        for (int fn = 0; fn < 2; ++fn)
#pragma unroll
          for (int ks = 0; ks < 2; ++ks)
            acc[fmBase + fm][fnBase + fn] = __builtin_amdgcn_mfma_f32_16x16x32_bf16(
                asbf(a[fm][ks]), asbf(b[fnBase + fn][ks]),
                acc[fmBase + fm][fnBase + fn], 0, 0, 0);
    };

#define TILE(C) do {                                                          \
    /* P1: rd a_lo + b_lo; stage A(t+1)h0 */                                  \
    DSRD(a[0][0], ardA[C][0], "0");     DSRD(a[0][1], ardA[C][1], "0");       \
    DSRD(a[1][0], ardA[C][0], "2048");  DSRD(a[1][1], ardA[C][1], "2048");    \
    DSRD(a[2][0], ardA[C][0], "4096");  DSRD(a[2][1], ardA[C][1], "4096");    \
    DSRD(a[3][0], ardA[C][0], "6144");  DSRD(a[3][1], ardA[C][1], "6144");    \
    DSRD(b[0][0], ardB[C][0], "0");     DSRD(b[0][1], ardB[C][1], "0");       \
    DSRD(b[1][0], ardB[C][0], "2048");  DSRD(b[1][1], ardB[C][1], "2048");    \
    stageA(C ^ 1, 0, _kA);                                                    \
    PBAR; LGKM0;                                                              \
    __builtin_amdgcn_s_setprio(1); mfmaQ(0, 0); __builtin_amdgcn_s_setprio(0);\
    SB0;                                                                      \
    /* P2: rd b_hi; stage A(t+1)h1 */                                         \
    DSRD(b[2][0], ardB[C][0], "4096");  DSRD(b[2][1], ardB[C][1], "4096");    \
    DSRD(b[3][0], ardB[C][0], "6144");  DSRD(b[3][1], ardB[C][1], "6144");    \
    stageA(C ^ 1, 1, _kA);                                                    \
    PBAR; LGKM0;                                                              \
    __builtin_amdgcn_s_setprio(1); mfmaQ(0, 2); __builtin_amdgcn_s_setprio(0);\
    SB0;                                                                      \
    /* P3: rd a_hi; barrier; THEN stage B(t+2)h0 (hazard fix) */              \
    DSRD(a[0][0], ardA[C][0], "8192");  DSRD(a[0][1], ardA[C][1], "8192");    \
    DSRD(a[1][0], ardA[C][0], "10240"); DSRD(a[1][1], ardA[C][1], "10240");   \
    DSRD(a[2][0], ardA[C][0], "12288"); DSRD(a[2][1], ardA[C][1], "12288");   \
    DSRD(a[3][0], ardA[C][0], "14336"); DSRD(a[3][1], ardA[C][1], "14336");   \
    PBAR; LGKM0;                                                              \
    stageB(C, 0, _kB);                                                        \
    SB0;                                                                      \
    __builtin_amdgcn_s_setprio(1); mfmaQ(4, 2); __builtin_amdgcn_s_setprio(0);\
    SB0;                                                                      \
    /* P4: stage B(t+2)h1; Q4 overlaps drain; counted vmcnt; barrier */       \
    stageB(C, 1, _kB);                                                        \
    SB0;                                                                      \
    __builtin_amdgcn_s_setprio(1); mfmaQ(4, 0); __builtin_amdgcn_s_setprio(0);\
    SB0;                                                                      \
    asm volatile("s_waitcnt vmcnt(4)" ::: "memory");                          \
    PBAR;                                                                     \
  } while (0)

    stageA(0, 0, 0); stageA(0, 1, 0);
    stageB(0, 0, 0); stageB(0, 1, 0);
    stageB(1, 0, 64); stageB(1, 1, 64);
    asm volatile("s_waitcnt vmcnt(4)" ::: "memory");
    PBAR;

    int _kA, _kB;
    for (int t = 0; t < NT; t += 2) {
      _kA = (t + 1 < NT ? t + 1 : NT - 1) * 64;
      _kB = (t + 2 < NT ? t + 2 : NT - 1) * 64;
      TILE(0);
      _kA = (t + 2 < NT ? t + 2 : NT - 1) * 64;
      _kB = (t + 3 < NT ? t + 3 : NT - 1) * 64;
      TILE(1);
    }
#undef TILE
    asm volatile("s_waitcnt vmcnt(0) lgkmcnt(0)" ::: "memory");

    float bb[4];
#pragma unroll
    for (int fn = 0; fn < 4; ++fn) bb[fn] = bias[n0 + wn * 64 + fn * 16 + r16];
    if (EPI == 0) {
#pragma unroll
      for (int fm = 0; fm < 8; ++fm) {
        const int grow = m0 + wm * 128 + fm * 16 + r4base;
#pragma unroll
        for (int fn = 0; fn < 4; ++fn) {
          const int gcol = n0 + wn * 64 + fn * 16 + r16;
          f32x4 v = acc[fm][fn];
#pragma unroll
          for (int i = 0; i < 4; ++i)
            Hout[(size_t)(grow + i) * K + gcol] = __float2bfloat16(gelu_exact(v[i] + bb[fn]));
        }
      }
    } else {
#pragma unroll
      for (int fm = 0; fm < 8; ++fm) {
        const int grow = m0 + wm * 128 + fm * 16 + r4base;
        int rid[4];
#pragma unroll
        for (int i = 0; i < 4; ++i) rid[i] = rowid[grow + i];
#pragma unroll
        for (int fn = 0; fn < 4; ++fn) {
          const int gcol = n0 + wn * 64 + fn * 16 + r16;
          f32x4 v = acc[fm][fn];
#pragma unroll
          for (int i = 0; i < 4; ++i) {
            if (rid[i] >= 0) {
              const size_t o = (size_t)rid[i] * K + gcol;
              Out[o] = resid[o] + v[i] + bb[fn];
            }
          }
        }
      }
    }
  } else {
    // ============== TAIL PATH (R11/R12/R15 verbatim, KSPLIT=4) ============
    const int tb = bid - 256;           // 0..127
    const int kp = tb & 3;
    const int n0 = ((tb >> 2) & 7) * 256;
    const int m0 = FULLROWS + (tb >> 5) * 128;
    const int kk0 = kp * 512;           // K range [kk0, kk0+512), 16 K-tiles
    const bool is_text = (m0 < Mt_pad);
    const short* Ag = (const short*)A;
    const short* Bg = (const short*)(is_text ? WTt : WTi);

    const int wm = w >> 2, wn = w & 3;
    const int sRowAdj = sg >> 2;
    const int sKAdj = (sg & 3) * 8;

    auto stageA = [&](int bI, int kk) {
      const int mr = w * 8 + srow8;
      const short* src = Ag + (size_t)(m0 + mr * 2 + sRowAdj) * K + kk + sKAdj;
      load_lds16(src, smem + bI * 8192 + w * 1024);
    };
    auto stageB = [&](int bI, int c2, int kk) {
      const int mr = c2 * 64 + w * 8 + srow8;
      const short* src = Bg + (size_t)(n0 + mr * 2 + sRowAdj) * K + kk + sKAdj;
      load_lds16(src, smem + 16384 + bI * 16384 + c2 * 8192 + w * 1024);
    };

    unsigned ardA[2], ardB[2];
#pragma unroll
    for (int bI = 0; bI < 2; ++bI) {
      ardA[bI] = sBase + bI * 8192u + (unsigned)(wm * 4096 + hl * 128 + gr * 16);
      ardB[bI] = sBase + 16384u + bI * 16384u + (unsigned)(wn * 4096 + hl * 128 + gr * 16);
    }

    i32x4 a[4], b[4];
    f32x4 acc[4][4];
    const f32x4 zero = {0.f, 0.f, 0.f, 0.f};
#pragma unroll
    for (int i = 0; i < 4; ++i)
#pragma unroll
      for (int j = 0; j < 4; ++j) acc[i][j] = zero;

#define RD_TILE(C) do {                                                   \
    DSRD(a[0], ardA[C], "0");    DSRD(a[1], ardA[C], "1024");             \
    DSRD(a[2], ardA[C], "2048"); DSRD(a[3], ardA[C], "3072");             \
    DSRD(b[0], ardB[C], "0");    DSRD(b[1], ardB[C], "1024");             \
    DSRD(b[2], ardB[C], "2048"); DSRD(b[3], ardB[C], "3072");             \
  } while (0)

    stageA(0, kk0);
    stageB(0, 0, kk0); stageB(0, 1, kk0);
    VM0;
    PBAR;

    for (int i = 0; i < 16; ++i) {
      const int c = i & 1;
      const int kn = kk0 + (i + 1 < 16 ? i + 1 : 15) * 32;
      stageA(c ^ 1, kn);
      stageB(c ^ 1, 0, kn); stageB(c ^ 1, 1, kn);
      RD_TILE(c);
      LGKM0;
      __builtin_amdgcn_s_setprio(1);
#pragma unroll
      for (int f = 0; f < 4; ++f)
#pragma unroll
        for (int fn = 0; fn < 4; ++fn)
          acc[f][fn] = __builtin_amdgcn_mfma_f32_16x16x32_bf16(
              asbf(a[f]), asbf(b[fn]), acc[f][fn], 0, 0, 0);
      __builtin_amdgcn_s_setprio(0);
      SB0;
      VM0;
      PBAR;
    }
#undef RD_TILE
    asm volatile("s_waitcnt vmcnt(0) lgkmcnt(0)" ::: "memory");

    // raw fp32 partial write: pp[kp][512][2048]
    float* ppk = pp + (size_t)kp * TAILROWS * H_DIM;
    const int mrel = m0 - FULLROWS;
#pragma unroll
    for (int fm = 0; fm < 4; ++fm) {
      const int prow = mrel + wm * 64 + fm * 16 + r4base;
#pragma unroll
      for (int fn = 0; fn < 4; ++fn) {
        const int gcol = n0 + wn * 64 + fn * 16 + r16;
        f32x4 v = acc[fm][fn];
#pragma unroll
        for (int i = 0; i < 4; ++i)
          ppk[(size_t)(prow + i) * H_DIM + gcol] = v[i];
      }
    }
  }
}

// ---------------------------------------------------------------------------
// Combine: sum 4 K-partials for tail rows 8192..8703, apply epilogue.
// ---------------------------------------------------------------------------
template <int EPI>
__global__ __launch_bounds__(256) void combine_kernel(
    const float* __restrict__ pp, const float* __restrict__ bt,
    const float* __restrict__ bi, const int* __restrict__ ctrl,
    const int* __restrict__ rowid, __hip_bfloat16* __restrict__ Hout,
    const float* __restrict__ resid, float* __restrict__ Out) {
  const int u = blockIdx.x * 256 + threadIdx.x;      // 0..262143
  const int r = u >> 9;                              // 0..511
  const int c = (u & 511) * 4;
  const size_t off = (size_t)r * H_DIM + c;
  float4 s = *(const float4*)(pp + off);
  const float4 s1 = *(const float4*)(pp + (size_t)TAILROWS * H_DIM + off);
  const float4 s2 = *(const float4*)(pp + (size_t)2 * TAILROWS * H_DIM + off);
  const float4 s3 = *(const float4*)(pp + (size_t)3 * TAILROWS * H_DIM + off);
  s.x += s1.x + s2.x + s3.x; s.y += s1.y + s2.y + s3.y;
  s.z += s1.z + s2.z + s3.z; s.w += s1.w + s2.w + s3.w;
  const int grow = FULLROWS + r;
  const float* bias = (grow < ctrl[1]) ? bt : bi;
  const float4 bb = *(const float4*)(bias + c);
  if (EPI == 0) {
    union { ushort u4[4]; ushort4 v4; } pk;
    float z[4] = {s.x + bb.x, s.y + bb.y, s.z + bb.z, s.w + bb.w};
#pragma unroll
    for (int j = 0; j < 4; ++j) {
      __hip_bfloat16 h = __float2bfloat16(0.5f * z[j] * (1.0f + erff(z[j] * 0.70710678118654752f)));
      pk.u4[j] = *(const ushort*)&h;
    }
    *(ushort4*)(Hout + (size_t)grow * H_DIM + c) = pk.v4;
  } else {
    const int rid = rowid[grow];
    if (rid >= 0) {
      const size_t o = (size_t)rid * H_DIM + c;
      const float4 rv = *(const float4*)(resid + o);
      float4 ov;
      ov.x = rv.x + s.x + bb.x; ov.y = rv.y + s.y + bb.y;
      ov.z = rv.z + s.z + bb.z; ov.w = rv.w + s.w + bb.w;
      *(float4*)(Out + o) = ov;
    }
  }
}

// ---------------------------------------------------------------------------
extern "C" void kernel_launch(void* const* d_in, const int* in_sizes, int n_in,
                              void* d_out, int out_size, void* d_ws, size_t ws_size,
                              hipStream_t stream) {
  const float* hidden = (const float*)d_in[0];
  const int*   tt     = (const int*)d_in[1];
  const float* gamma  = (const float*)d_in[2];
  const float* beta   = (const float*)d_in[3];
  const float* tw1    = (const float*)d_in[4];
  const float* tb1    = (const float*)d_in[5];
  const float* tw2    = (const float*)d_in[6];
  const float* tb2    = (const float*)d_in[7];
  const float* iw1    = (const float*)d_in[8];
  const float* ib1    = (const float*)d_in[9];
  const float* iw2    = (const float*)d_in[10];
  const float* ib2    = (const float*)d_in[11];
  float* out = (float*)d_out;

  const int T = in_sizes[1];          // 8192 tokens
  const int K = H_DIM;
  const int maxrows = FULLROWS + TAILROWS;   // 8704

  char* ws = (char*)d_ws;
  int* ctrl  = (int*)(ws);
  int* pos   = (int*)(ws + 4096);
  int* rowid = (int*)(ws + 65536);
  const size_t WOFF = 131072;
  const size_t WSZ = (size_t)K * K * sizeof(__hip_bfloat16);
  __hip_bfloat16* tw1T = (__hip_bfloat16*)(ws + WOFF);
  __hip_bfloat16* tw2T = (__hip_bfloat16*)(ws + WOFF + WSZ);
  __hip_bfloat16* iw1T = (__hip_bfloat16*)(ws + WOFF + 2 * WSZ);
  __hip_bfloat16* iw2T = (__hip_bfloat16*)(ws + WOFF + 3 * WSZ);
  __hip_bfloat16* xg   = (__hip_bfloat16*)(ws + WOFF + 4 * WSZ);
  __hip_bfloat16* hb   = xg + (size_t)maxrows * K;
  float* pp = (float*)(hb + (size_t)maxrows * K);   // 4*512*2048 fp32 = 16.8 MB

  partition_kernel<<<1, 256, 0, stream>>>(tt, T, ctrl, pos, rowid);
  pad_zero_kernel<<<512, 256, 0, stream>>>(ctrl, xg);

  dim3 tg(K / 32, K / 32, 4);
  transpose_to_bf16_x4<<<tg, 256, 0, stream>>>(tw1, tw2, iw1, iw2,
                                               tw1T, tw2T, iw1T, iw2T);

  ln_scatter_kernel<<<T, 256, 0, stream>>>(hidden, gamma, beta, pos, xg);

  gemmk<0><<<384, 512, 0, stream>>>(xg, tw1T, iw1T, tb1, ib1, ctrl, rowid,
                                    hb, nullptr, nullptr, pp);
  combine_kernel<0><<<1024, 256, 0, stream>>>(pp, tb1, ib1, ctrl, rowid,
                                              hb, nullptr, nullptr);
  gemmk<1><<<384, 512, 0, stream>>>(hb, tw2T, iw2T, tb2, ib2, ctrl, rowid,
                                    nullptr, hidden, out, pp);
  combine_kernel<1><<<1024, 256, 0, stream>>>(pp, tb2, ib2, ctrl, rowid,
                                              nullptr, hidden, out);
}

// Round 17
// 253.852 us; speedup vs baseline: 1.0819x; 1.0029x over previous
//
#include <hip/hip_runtime.h>
#include <hip/hip_bf16.h>

// ---------------------------------------------------------------------------
// MVoT token processor: out = hidden + MLP_{type}(LN(hidden)), type in {0,1}
// R17 = R16 with the full-path TILE reduced to the hazard-minimal 2 barriers
// per K-tile: PBAR_P3 (B-read/stageB cross-wave WAR) + PBAR_P4end (staged-
// data visibility after counted vmcnt). A staged both-halves at P1 (3-phase
// HBM cover), B both-halves at P3, Q3+Q4 merged (32-MFMA cluster).
// ---------------------------------------------------------------------------

#define H_DIM 2048
#define FULLROWS 8192
#define TAILROWS 512

typedef __attribute__((ext_vector_type(8))) short s16x8;   // 8 bf16 (4 VGPRs)
typedef __attribute__((ext_vector_type(4))) float f32x4;   // MFMA accumulator
typedef __attribute__((ext_vector_type(4))) int   i32x4;   // asm ds_read dst

typedef __attribute__((address_space(1))) const unsigned int gu32;
typedef __attribute__((address_space(3))) unsigned int lu32;
typedef __attribute__((address_space(3))) short lds_s;

__device__ __forceinline__ void load_lds16(const void* g, void* l) {
  __builtin_amdgcn_global_load_lds((gu32*)g, (lu32*)l, 16, 0, 0);
}

__device__ __forceinline__ s16x8 asbf(i32x4 v) {
  union { i32x4 i; s16x8 s; } u; u.i = v; return u.s;
}

// ---------------------------------------------------------------------------
// Partition (R2/R12-verified): text first, each group padded to 256 rows.
// ctrl: [0]=Mt [1]=Mt_pad [2]=Mi [3]=Mi_pad [4]=total_rows
// ---------------------------------------------------------------------------
__global__ __launch_bounds__(256) void partition_kernel(
    const int* __restrict__ tt, int T, int* __restrict__ ctrl,
    int* __restrict__ pos, int* __restrict__ rowid) {
  __shared__ int psum[256];
  const int tid = threadIdx.x;
  const int npt = T >> 8;
  const int base = tid * npt;
  int cnt = 0;
  for (int i = 0; i < npt; ++i) cnt += (tt[base + i] == 0);
  psum[tid] = cnt;
  __syncthreads();
  for (int off = 1; off < 256; off <<= 1) {
    int v = psum[tid];
    int add = (tid >= off) ? psum[tid - off] : 0;
    __syncthreads();
    psum[tid] = v + add;
    __syncthreads();
  }
  const int Mt = psum[255];
  const int Mt_pad = (Mt + 255) & ~255;
  int tpos = psum[tid] - cnt;
  int ipos = base - tpos;
  for (int i = 0; i < npt; ++i) {
    const int tok = base + i;
    int p;
    if (tt[tok] == 0) p = tpos++;
    else              p = Mt_pad + ipos++;
    pos[tok] = p;
    rowid[p] = tok;
  }
  const int Mi = T - Mt;
  const int Mi_pad = (Mi + 255) & ~255;
  for (int g = Mt + tid; g < Mt_pad; g += 256) rowid[g] = -1;
  for (int g = Mt_pad + Mi + tid; g < Mt_pad + Mi_pad; g += 256) rowid[g] = -1;
  for (int g = Mt_pad + Mi_pad + tid; g < FULLROWS + TAILROWS; g += 256)
    rowid[g] = -1;
  if (tid == 0) {
    ctrl[0] = Mt; ctrl[1] = Mt_pad; ctrl[2] = Mi; ctrl[3] = Mi_pad;
    ctrl[4] = Mt_pad + Mi_pad;
  }
}

// ---------------------------------------------------------------------------
// Zero exactly the xg rows LN doesn't write (R13/R15-verified).
// ---------------------------------------------------------------------------
__global__ __launch_bounds__(256) void pad_zero_kernel(
    const int* __restrict__ ctrl, __hip_bfloat16* __restrict__ XG) {
  const int Mt = ctrl[0], Mt_pad = ctrl[1], Mi = ctrl[2];
  const int n1 = Mt_pad - Mt;
  const int start2 = Mt_pad + Mi;
  const int b = blockIdx.x;
  int row;
  if (b < n1) row = Mt + b;
  else {
    const int b2 = b - n1;
    if (start2 + b2 >= FULLROWS + TAILROWS) return;
    row = start2 + b2;
  }
  const int4 z = {0, 0, 0, 0};
  *(int4*)(XG + (size_t)row * H_DIM + threadIdx.x * 8) = z;
}

// ---------------------------------------------------------------------------
// Fused weight transpose + fp32->bf16 for all 4 matrices (grid.z selects).
// ---------------------------------------------------------------------------
__global__ __launch_bounds__(256) void transpose_to_bf16_x4(
    const float* __restrict__ W0, const float* __restrict__ W1,
    const float* __restrict__ W2, const float* __restrict__ W3,
    __hip_bfloat16* __restrict__ O0, __hip_bfloat16* __restrict__ O1,
    __hip_bfloat16* __restrict__ O2, __hip_bfloat16* __restrict__ O3) {
  __shared__ float tile[32][33];
  const int bx = blockIdx.x, by = blockIdx.y, bz = blockIdx.z;
  const float* W = (bz == 0) ? W0 : (bz == 1) ? W1 : (bz == 2) ? W2 : W3;
  __hip_bfloat16* WT = (bz == 0) ? O0 : (bz == 1) ? O1 : (bz == 2) ? O2 : O3;
  const int tid = threadIdx.x;
  const int r = tid >> 3, c4 = (tid & 7) * 4;
  const float4 v = *(const float4*)(W + (size_t)(by * 32 + r) * H_DIM + bx * 32 + c4);
  tile[r][c4 + 0] = v.x; tile[r][c4 + 1] = v.y;
  tile[r][c4 + 2] = v.z; tile[r][c4 + 3] = v.w;
  __syncthreads();
  union { ushort u[4]; ushort4 v4; } pk;
#pragma unroll
  for (int j = 0; j < 4; ++j) {
    __hip_bfloat16 h = __float2bfloat16(tile[c4 + j][r]);
    pk.u[j] = *(const ushort*)&h;
  }
  *(ushort4*)(WT + (size_t)(bx * 32 + r) * H_DIM + by * 32 + c4) = pk.v4;
}

// ---------------------------------------------------------------------------
// LayerNorm (fp32) -> bf16, scatter row to its gathered position.
// ---------------------------------------------------------------------------
__global__ __launch_bounds__(256) void ln_scatter_kernel(
    const float* __restrict__ X, const float* __restrict__ gamma,
    const float* __restrict__ beta, const int* __restrict__ pos,
    __hip_bfloat16* __restrict__ XG) {
  const int t = blockIdx.x, tid = threadIdx.x;
  const float* row = X + (size_t)t * H_DIM;
  float x[8];
  {
    float4 v0 = *(const float4*)(row + tid * 8);
    float4 v1 = *(const float4*)(row + tid * 8 + 4);
    x[0] = v0.x; x[1] = v0.y; x[2] = v0.z; x[3] = v0.w;
    x[4] = v1.x; x[5] = v1.y; x[6] = v1.z; x[7] = v1.w;
  }
  float s = 0.f, q = 0.f;
#pragma unroll
  for (int j = 0; j < 8; ++j) { s += x[j]; q += x[j] * x[j]; }
#pragma unroll
  for (int off = 32; off > 0; off >>= 1) {
    s += __shfl_down(s, off);
    q += __shfl_down(q, off);
  }
  __shared__ float ls[4], lq[4];
  if ((tid & 63) == 0) { ls[tid >> 6] = s; lq[tid >> 6] = q; }
  __syncthreads();
  const float S = ls[0] + ls[1] + ls[2] + ls[3];
  const float Q = lq[0] + lq[1] + lq[2] + lq[3];
  const float mu = S * (1.0f / H_DIM);
  const float var = Q * (1.0f / H_DIM) - mu * mu;
  const float rstd = rsqrtf(var + 1e-12f);
  const int p = pos[t];
  float4 g0 = *(const float4*)(gamma + tid * 8);
  float4 g1 = *(const float4*)(gamma + tid * 8 + 4);
  float4 b0 = *(const float4*)(beta + tid * 8);
  float4 b1 = *(const float4*)(beta + tid * 8 + 4);
  float g[8] = {g0.x, g0.y, g0.z, g0.w, g1.x, g1.y, g1.z, g1.w};
  float b[8] = {b0.x, b0.y, b0.z, b0.w, b1.x, b1.y, b1.z, b1.w};
  union { ushort u[8]; int4 v; } pk;
#pragma unroll
  for (int j = 0; j < 8; ++j) {
    float y = (x[j] - mu) * rstd * g[j] + b[j];
    __hip_bfloat16 h = __float2bfloat16(y);
    pk.u[j] = *(const ushort*)&h;
  }
  *(int4*)(XG + (size_t)p * H_DIM + tid * 8) = pk.v;
}

// --- asm helpers -----------------------------------------------------------
#define DSRD(dst, addr, OFF) \
  asm volatile("ds_read_b128 %0, %1 offset:" OFF : "=v"(dst) : "v"(addr))
#define PBAR asm volatile("s_barrier" ::: "memory")
#define SB0  __builtin_amdgcn_sched_barrier(0)
#define LGKM0 do { \
  asm volatile("s_waitcnt lgkmcnt(0)" ::: "memory"); SB0; } while (0)
#define VM0 asm volatile("s_waitcnt vmcnt(0)" ::: "memory")

__device__ __forceinline__ float gelu_exact(float z) {
  return 0.5f * z * (1.0f + erff(z * 0.70710678118654752f));
}

// ---------------------------------------------------------------------------
// Unified GEMM, grid = 384 x 512 thr:
//  bid < 256: FULL path, hazard-minimal 2-barrier TILE:
//   P1: rd a_lo(8)+b_lo(4); stageA(h0)+stageA(h1) | lgkm0 | Q1
//   P2: rd b_hi(4)                                | lgkm0 | Q2
//   P3: rd a_hi(8) | PBAR | lgkm0 | stageB(h0)+stageB(h1) | Q3 | Q4
//       | vmcnt(4) | PBAR
//   Hazard set (audited under inter-barrier drift):
//    - PBAR_P3: all waves' B-reads (P1/P2, retired by wave-local lgkm0
//      before arrival) precede stageB(C) overwrites [cross-wave WAR].
//    - PBAR_end: after each wave's vmcnt(4), so all staged t+1 data is
//      visible before t+1's reads.
//    - stageA(C^1)@P1 conflicts with no in-tile reader (A reads target
//      buf C only); its buffer's last readers retired 2 barriers earlier.
//   vmcnt(4)@end: 12 outstanding (B(t+1):4, A(t+1):4, B(t+2):4) ->
//   drains B(t+1)+A(t+1) (needed next tile), leaves B(t+2). Never 0.
//  bid >= 256: TAIL path (R11/R12/R15-verbatim, KSPLIT=4).
// ---------------------------------------------------------------------------
template <int EPI>
__global__ __launch_bounds__(512, 2) void gemmk(
    const __hip_bfloat16* __restrict__ A,
    const __hip_bfloat16* __restrict__ WTt, const __hip_bfloat16* __restrict__ WTi,
    const float* __restrict__ bt, const float* __restrict__ bi,
    const int* __restrict__ ctrl, const int* __restrict__ rowid,
    __hip_bfloat16* __restrict__ Hout,
    const float* __restrict__ resid, float* __restrict__ Out,
    float* __restrict__ pp) {
  constexpr int K = H_DIM;
  const int Mt_pad = ctrl[1];

  __shared__ __align__(16) char smem[131072];
  const unsigned sBase = (unsigned)(uintptr_t)(lds_s*)smem;

  const int tid = threadIdx.x;
  const int w = tid >> 6, l = tid & 63;
  const int bid = blockIdx.x;

  const int srow8 = l >> 3;
  const int sg = (l & 7) ^ srow8;
  const int r16 = l & 15;
  const int r4base = (l >> 4) * 4;
  const int hl = (l & 15) >> 1;
  const int gr = (((l & 1) << 2) | (l >> 4)) ^ hl;

  if (bid < 256) {
    // ===================== FULL PATH (2-barrier TILE) =====================
    constexpr int NT = K / 64;          // 32 K-tiles
    const int m0 = (bid >> 3) * 256;
    const int n0 = (bid & 7) * 256;
    const bool is_text = (m0 < Mt_pad);
    const short* Ag = (const short*)A;
    const short* Bg = (const short*)(is_text ? WTt : WTi);
    const float* bias = is_text ? bt : bi;

    const int wm = w >> 2, wn = w & 3;
    const int scol8 = sg * 8;

    auto stageA = [&](int bI, int h, int kk) {
#pragma unroll
      for (int c = 0; c < 2; ++c) {
        const short* src = Ag + (size_t)(m0 + h * 128 + c * 64 + w * 8 + srow8) * K + kk + scol8;
        load_lds16(src, smem + bI * 32768 + h * 16384 + (c * 4096 + w * 512) * 2);
      }
    };
    auto stageB = [&](int bI, int h, int kk) {
#pragma unroll
      for (int c = 0; c < 2; ++c) {
        const short* src = Bg + (size_t)(n0 + h * 128 + c * 64 + w * 8 + srow8) * K + kk + scol8;
        load_lds16(src, smem + 65536 + bI * 32768 + h * 16384 + (c * 4096 + w * 512) * 2);
      }
    };

    int off2[2];
#pragma unroll
    for (int ks = 0; ks < 2; ++ks)
      off2[ks] = r16 * 64 + (((ks * 4 + (l >> 4)) ^ (l & 7)) * 8);

    unsigned ardA[2][2], ardB[2][2];
#pragma unroll
    for (int bI = 0; bI < 2; ++bI)
#pragma unroll
      for (int ks = 0; ks < 2; ++ks) {
        ardA[bI][ks] = sBase + bI * 32768u + (unsigned)(wm * 16384 + off2[ks] * 2);
        ardB[bI][ks] = sBase + 65536u + bI * 32768u +
                       (unsigned)((wn >> 1) * 16384 + ((wn & 1) * 4096 + off2[ks] * 1) * 2);
      }

    i32x4 a[4][2], b[4][2];
    f32x4 acc[8][4];
    const f32x4 zero = {0.f, 0.f, 0.f, 0.f};
#pragma unroll
    for (int i = 0; i < 8; ++i)
#pragma unroll
      for (int j = 0; j < 4; ++j) acc[i][j] = zero;

    auto mfmaQ = [&](int fmBase, int fnBase) {
#pragma unroll
      for (int fm = 0; fm < 4; ++fm)
#pragma unroll
        for (int fn = 0; fn < 2; ++fn)
#pragma unroll
          for (int ks = 0; ks < 2; ++ks)
            acc[fmBase + fm][fnBase + fn] = __builtin_amdgcn_mfma_f32_16x16x32_bf16(
                asbf(a[fm][ks]), asbf(b[fnBase + fn][ks]),
                acc[fmBase + fm][fnBase + fn], 0, 0, 0);
    };

#define TILE(C) do {                                                          \
    /* P1: rd a_lo + b_lo; stage BOTH A(t+1) halves (3-phase cover) */        \
    DSRD(a[0][0], ardA[C][0], "0");     DSRD(a[0][1], ardA[C][1], "0");       \
    DSRD(a[1][0], ardA[C][0], "2048");  DSRD(a[1][1], ardA[C][1], "2048");    \
    DSRD(a[2][0], ardA[C][0], "4096");  DSRD(a[2][1], ardA[C][1], "4096");    \
    DSRD(a[3][0], ardA[C][0], "6144");  DSRD(a[3][1], ardA[C][1], "6144");    \
    DSRD(b[0][0], ardB[C][0], "0");     DSRD(b[0][1], ardB[C][1], "0");       \
    DSRD(b[1][0], ardB[C][0], "2048");  DSRD(b[1][1], ardB[C][1], "2048");    \
    stageA(C ^ 1, 0, _kA); stageA(C ^ 1, 1, _kA);                             \
    LGKM0;                                                                    \
    __builtin_amdgcn_s_setprio(1); mfmaQ(0, 0); __builtin_amdgcn_s_setprio(0);\
    SB0;                                                                      \
    /* P2: rd b_hi */                                                         \
    DSRD(b[2][0], ardB[C][0], "4096");  DSRD(b[2][1], ardB[C][1], "4096");    \
    DSRD(b[3][0], ardB[C][0], "6144");  DSRD(b[3][1], ardB[C][1], "6144");    \
    LGKM0;                                                                    \
    __builtin_amdgcn_s_setprio(1); mfmaQ(0, 2); __builtin_amdgcn_s_setprio(0);\
    SB0;                                                                      \
    /* P3: rd a_hi; BARRIER (B-read/stageB WAR); stage BOTH B(t+2) halves */  \
    DSRD(a[0][0], ardA[C][0], "8192");  DSRD(a[0][1], ardA[C][1], "8192");    \
    DSRD(a[1][0], ardA[C][0], "10240"); DSRD(a[1][1], ardA[C][1], "10240");   \
    DSRD(a[2][0], ardA[C][0], "12288"); DSRD(a[2][1], ardA[C][1], "12288");   \
    DSRD(a[3][0], ardA[C][0], "14336"); DSRD(a[3][1], ardA[C][1], "14336");   \
    PBAR; LGKM0;                                                              \
    stageB(C, 0, _kB); stageB(C, 1, _kB);                                     \
    SB0;                                                                      \
    __builtin_amdgcn_s_setprio(1); mfmaQ(4, 2); mfmaQ(4, 0);                  \
    __builtin_amdgcn_s_setprio(0);                                            \
    SB0;                                                                      \
    asm volatile("s_waitcnt vmcnt(4)" ::: "memory");                          \
    PBAR;                                                                     \
  } while (0)

    stageA(0, 0, 0); stageA(0, 1, 0);
    stageB(0, 0, 0); stageB(0, 1, 0);
    stageB(1, 0, 64); stageB(1, 1, 64);
    asm volatile("s_waitcnt vmcnt(4)" ::: "memory");
    PBAR;

    int _kA, _kB;
    for (int t = 0; t < NT; t += 2) {
      _kA = (t + 1 < NT ? t + 1 : NT - 1) * 64;
      _kB = (t + 2 < NT ? t + 2 : NT - 1) * 64;
      TILE(0);
      _kA = (t + 2 < NT ? t + 2 : NT - 1) * 64;
      _kB = (t + 3 < NT ? t + 3 : NT - 1) * 64;
      TILE(1);
    }
#undef TILE
    asm volatile("s_waitcnt vmcnt(0) lgkmcnt(0)" ::: "memory");

    float bb[4];
#pragma unroll
    for (int fn = 0; fn < 4; ++fn) bb[fn] = bias[n0 + wn * 64 + fn * 16 + r16];
    if (EPI == 0) {
#pragma unroll
      for (int fm = 0; fm < 8; ++fm) {
        const int grow = m0 + wm * 128 + fm * 16 + r4base;
#pragma unroll
        for (int fn = 0; fn < 4; ++fn) {
          const int gcol = n0 + wn * 64 + fn * 16 + r16;
          f32x4 v = acc[fm][fn];
#pragma unroll
          for (int i = 0; i < 4; ++i)
            Hout[(size_t)(grow + i) * K + gcol] = __float2bfloat16(gelu_exact(v[i] + bb[fn]));
        }
      }
    } else {
#pragma unroll
      for (int fm = 0; fm < 8; ++fm) {
        const int grow = m0 + wm * 128 + fm * 16 + r4base;
        int rid[4];
#pragma unroll
        for (int i = 0; i < 4; ++i) rid[i] = rowid[grow + i];
#pragma unroll
        for (int fn = 0; fn < 4; ++fn) {
          const int gcol = n0 + wn * 64 + fn * 16 + r16;
          f32x4 v = acc[fm][fn];
#pragma unroll
          for (int i = 0; i < 4; ++i) {
            if (rid[i] >= 0) {
              const size_t o = (size_t)rid[i] * K + gcol;
              Out[o] = resid[o] + v[i] + bb[fn];
            }
          }
        }
      }
    }
  } else {
    // ============== TAIL PATH (R11/R12/R15 verbatim, KSPLIT=4) ============
    const int tb = bid - 256;           // 0..127
    const int kp = tb & 3;
    const int n0 = ((tb >> 2) & 7) * 256;
    const int m0 = FULLROWS + (tb >> 5) * 128;
    const int kk0 = kp * 512;           // K range [kk0, kk0+512), 16 K-tiles
    const bool is_text = (m0 < Mt_pad);
    const short* Ag = (const short*)A;
    const short* Bg = (const short*)(is_text ? WTt : WTi);

    const int wm = w >> 2, wn = w & 3;
    const int sRowAdj = sg >> 2;
    const int sKAdj = (sg & 3) * 8;

    auto stageA = [&](int bI, int kk) {
      const int mr = w * 8 + srow8;
      const short* src = Ag + (size_t)(m0 + mr * 2 + sRowAdj) * K + kk + sKAdj;
      load_lds16(src, smem + bI * 8192 + w * 1024);
    };
    auto stageB = [&](int bI, int c2, int kk) {
      const int mr = c2 * 64 + w * 8 + srow8;
      const short* src = Bg + (size_t)(n0 + mr * 2 + sRowAdj) * K + kk + sKAdj;
      load_lds16(src, smem + 16384 + bI * 16384 + c2 * 8192 + w * 1024);
    };

    unsigned ardA[2], ardB[2];
#pragma unroll
    for (int bI = 0; bI < 2; ++bI) {
      ardA[bI] = sBase + bI * 8192u + (unsigned)(wm * 4096 + hl * 128 + gr * 16);
      ardB[bI] = sBase + 16384u + bI * 16384u + (unsigned)(wn * 4096 + hl * 128 + gr * 16);
    }

    i32x4 a[4], b[4];
    f32x4 acc[4][4];
    const f32x4 zero = {0.f, 0.f, 0.f, 0.f};
#pragma unroll
    for (int i = 0; i < 4; ++i)
#pragma unroll
      for (int j = 0; j < 4; ++j) acc[i][j] = zero;

#define RD_TILE(C) do {                                                   \
    DSRD(a[0], ardA[C], "0");    DSRD(a[1], ardA[C], "1024");             \
    DSRD(a[2], ardA[C], "2048"); DSRD(a[3], ardA[C], "3072");             \
    DSRD(b[0], ardB[C], "0");    DSRD(b[1], ardB[C], "1024");             \
    DSRD(b[2], ardB[C], "2048"); DSRD(b[3], ardB[C], "3072");             \
  } while (0)

    stageA(0, kk0);
    stageB(0, 0, kk0); stageB(0, 1, kk0);
    VM0;
    PBAR;

    for (int i = 0; i < 16; ++i) {
      const int c = i & 1;
      const int kn = kk0 + (i + 1 < 16 ? i + 1 : 15) * 32;
      stageA(c ^ 1, kn);
      stageB(c ^ 1, 0, kn); stageB(c ^ 1, 1, kn);
      RD_TILE(c);
      LGKM0;
      __builtin_amdgcn_s_setprio(1);
#pragma unroll
      for (int f = 0; f < 4; ++f)
#pragma unroll
        for (int fn = 0; fn < 4; ++fn)
          acc[f][fn] = __builtin_amdgcn_mfma_f32_16x16x32_bf16(
              asbf(a[f]), asbf(b[fn]), acc[f][fn], 0, 0, 0);
      __builtin_amdgcn_s_setprio(0);
      SB0;
      VM0;
      PBAR;
    }
#undef RD_TILE
    asm volatile("s_waitcnt vmcnt(0) lgkmcnt(0)" ::: "memory");

    // raw fp32 partial write: pp[kp][512][2048]
    float* ppk = pp + (size_t)kp * TAILROWS * H_DIM;
    const int mrel = m0 - FULLROWS;
#pragma unroll
    for (int fm = 0; fm < 4; ++fm) {
      const int prow = mrel + wm * 64 + fm * 16 + r4base;
#pragma unroll
      for (int fn = 0; fn < 4; ++fn) {
        const int gcol = n0 + wn * 64 + fn * 16 + r16;
        f32x4 v = acc[fm][fn];
#pragma unroll
        for (int i = 0; i < 4; ++i)
          ppk[(size_t)(prow + i) * H_DIM + gcol] = v[i];
      }
    }
  }
}

// ---------------------------------------------------------------------------
// Combine: sum 4 K-partials for tail rows 8192..8703, apply epilogue.
// ---------------------------------------------------------------------------
template <int EPI>
__global__ __launch_bounds__(256) void combine_kernel(
    const float* __restrict__ pp, const float* __restrict__ bt,
    const float* __restrict__ bi, const int* __restrict__ ctrl,
    const int* __restrict__ rowid, __hip_bfloat16* __restrict__ Hout,
    const float* __restrict__ resid, float* __restrict__ Out) {
  const int u = blockIdx.x * 256 + threadIdx.x;      // 0..262143
  const int r = u >> 9;                              // 0..511
  const int c = (u & 511) * 4;
  const size_t off = (size_t)r * H_DIM + c;
  float4 s = *(const float4*)(pp + off);
  const float4 s1 = *(const float4*)(pp + (size_t)TAILROWS * H_DIM + off);
  const float4 s2 = *(const float4*)(pp + (size_t)2 * TAILROWS * H_DIM + off);
  const float4 s3 = *(const float4*)(pp + (size_t)3 * TAILROWS * H_DIM + off);
  s.x += s1.x + s2.x + s3.x; s.y += s1.y + s2.y + s3.y;
  s.z += s1.z + s2.z + s3.z; s.w += s1.w + s2.w + s3.w;
  const int grow = FULLROWS + r;
  const float* bias = (grow < ctrl[1]) ? bt : bi;
  const float4 bb = *(const float4*)(bias + c);
  if (EPI == 0) {
    union { ushort u4[4]; ushort4 v4; } pk;
    float z[4] = {s.x + bb.x, s.y + bb.y, s.z + bb.z, s.w + bb.w};
#pragma unroll
    for (int j = 0; j < 4; ++j) {
      __hip_bfloat16 h = __float2bfloat16(0.5f * z[j] * (1.0f + erff(z[j] * 0.70710678118654752f)));
      pk.u4[j] = *(const ushort*)&h;
    }
    *(ushort4*)(Hout + (size_t)grow * H_DIM + c) = pk.v4;
  } else {
    const int rid = rowid[grow];
    if (rid >= 0) {
      const size_t o = (size_t)rid * H_DIM + c;
      const float4 rv = *(const float4*)(resid + o);
      float4 ov;
      ov.x = rv.x + s.x + bb.x; ov.y = rv.y + s.y + bb.y;
      ov.z = rv.z + s.z + bb.z; ov.w = rv.w + s.w + bb.w;
      *(float4*)(Out + o) = ov;
    }
  }
}

// ---------------------------------------------------------------------------
extern "C" void kernel_launch(void* const* d_in, const int* in_sizes, int n_in,
                              void* d_out, int out_size, void* d_ws, size_t ws_size,
                              hipStream_t stream) {
  const float* hidden = (const float*)d_in[0];
  const int*   tt     = (const int*)d_in[1];
  const float* gamma  = (const float*)d_in[2];
  const float* beta   = (const float*)d_in[3];
  const float* tw1    = (const float*)d_in[4];
  const float* tb1    = (const float*)d_in[5];
  const float* tw2    = (const float*)d_in[6];
  const float* tb2    = (const float*)d_in[7];
  const float* iw1    = (const float*)d_in[8];
  const float* ib1    = (const float*)d_in[9];
  const float* iw2    = (const float*)d_in[10];
  const float* ib2    = (const float*)d_in[11];
  float* out = (float*)d_out;

  const int T = in_sizes[1];          // 8192 tokens
  const int K = H_DIM;
  const int maxrows = FULLROWS + TAILROWS;   // 8704

  char* ws = (char*)d_ws;
  int* ctrl  = (int*)(ws);
  int* pos   = (int*)(ws + 4096);
  int* rowid = (int*)(ws + 65536);
  const size_t WOFF = 131072;
  const size_t WSZ = (size_t)K * K * sizeof(__hip_bfloat16);
  __hip_bfloat16* tw1T = (__hip_bfloat16*)(ws + WOFF);
  __hip_bfloat16* tw2T = (__hip_bfloat16*)(ws + WOFF + WSZ);
  __hip_bfloat16* iw1T = (__hip_bfloat16*)(ws + WOFF + 2 * WSZ);
  __hip_bfloat16* iw2T = (__hip_bfloat16*)(ws + WOFF + 3 * WSZ);
  __hip_bfloat16* xg   = (__hip_bfloat16*)(ws + WOFF + 4 * WSZ);
  __hip_bfloat16* hb   = xg + (size_t)maxrows * K;
  float* pp = (float*)(hb + (size_t)maxrows * K);   // 4*512*2048 fp32 = 16.8 MB

  partition_kernel<<<1, 256, 0, stream>>>(tt, T, ctrl, pos, rowid);
  pad_zero_kernel<<<512, 256, 0, stream>>>(ctrl, xg);

  dim3 tg(K / 32, K / 32, 4);
  transpose_to_bf16_x4<<<tg, 256, 0, stream>>>(tw1, tw2, iw1, iw2,
                                               tw1T, tw2T, iw1T, iw2T);

  ln_scatter_kernel<<<T, 256, 0, stream>>>(hidden, gamma, beta, pos, xg);

  gemmk<0><<<384, 512, 0, stream>>>(xg, tw1T, iw1T, tb1, ib1, ctrl, rowid,
                                    hb, nullptr, nullptr, pp);
  combine_kernel<0><<<1024, 256, 0, stream>>>(pp, tb1, ib1, ctrl, rowid,
                                              hb, nullptr, nullptr);
  gemmk<1><<<384, 512, 0, stream>>>(hb, tw2T, iw2T, tb2, ib2, ctrl, rowid,
                                    nullptr, hidden, out, pp);
  combine_kernel<1><<<1024, 256, 0, stream>>>(pp, tb2, ib2, ctrl, rowid,
                                              nullptr, hidden, out);
}